// Round 5
// baseline (8025.976 us; speedup 1.0000x reference)
//
#include <hip/hip_runtime.h>
#include <math.h>

// Round 9b: identical resubmit of round 9 (bench infra failed twice; no
// measurement happened). Dual-stream waves: 2 independent batches per wave,
// phase-interleaved.
//  - r8 post-mortem: packed-f32 cut VALU ops, dur flat -> NOT issue-bound.
//    Per-SIMD pipes ~16% busy; 64k cycles/step vs ~6k critical path = pure
//    latency-bound serial chain at 2 waves/SIMD. r6 proved M-split+barriers
//    can't fix it (same chain length + sync).
//  - r9: ILP instead of TLP. Each wave runs TWO batches, interleaved at phase
//    granularity (stats-A/stats-B/LN1-A/LN1-B/...). Stream B's instructions
//    cover stream A's DPP chains, LDS round-trip latency, MFMA latency.
//    Weight/bias fragments are loaded ONCE and feed both streams (halves
//    per-batch LDS weight traffic).
//  - 1024 waves, 4-wave/256-thr blocks, 256 blocks = 1/CU. LDS: 120KB weights
//    + 4x8KB scratch + 6.5KB bias = 158.4KB. 1 wave/SIMD; launch_bounds(256,1)
//    -> full VGPR budget, no spills. il-loop rolled to keep body I-cache-sized.
//
// Fragment layouts (gfx950, verified rounds 2-8, bit-identical here):
//   A[m=lane&15][k=(lane>>4)*8+j], B[k=(lane>>4)*8+j][n=lane&15],
//   C: col=lane&15, row=(lane>>4)*4+reg.

namespace {
constexpr int Tt = 256, NL = 3;

typedef float    f32x4 __attribute__((ext_vector_type(4)));
typedef _Float16 half2 __attribute__((ext_vector_type(2)));
typedef _Float16 h16x4 __attribute__((ext_vector_type(4)));
typedef _Float16 h16x8 __attribute__((ext_vector_type(8)));

#define MFMA16(a, b, c) __builtin_amdgcn_mfma_f32_16x16x32_f16((a), (b), (c), 0, 0, 0)

__device__ __forceinline__ half2 h2c(float v) { return (half2)((_Float16)v); }
__device__ __forceinline__ f32x4 f4s(float v) { return (f32x4)v; }
__device__ __forceinline__ half2 pkrtz(float a, float b) {
    return __builtin_bit_cast(half2, __builtin_amdgcn_cvt_pkrtz(a, b));
}
__device__ __forceinline__ void st4h(short* p, half2 a, half2 b) {
    uint2 v;
    v.x = __builtin_bit_cast(unsigned int, a);
    v.y = __builtin_bit_cast(unsigned int, b);
    *(uint2*)p = v;
}
// packed f16 GELU, no transcendentals. s scaled by 1/8 to keep c4 normal in f16.
__device__ __forceinline__ half2 gelu_pk(half2 x) {
    half2 tc = __builtin_elementwise_min(__builtin_elementwise_max(x, h2c(-3.0f)), h2c(3.0f));
    half2 s = (tc * tc) * h2c(0.125f);
    half2 p = s * h2c(0.1455169f) + h2c(-0.446340f);
    p = s * p + h2c(0.604927f);
    p = s * p + h2c(-0.529702f);
    p = s * p + h2c(0.3989423f);
    return x * (h2c(0.5f) + tc * p);
}
// scalar f32 version (phys MLP pre-pass)
__device__ __forceinline__ float gelu_f(float x) {
    float tc = fminf(fmaxf(x, -3.f), 3.f);
    float s = tc * tc;
    float p = fmaf(s, 3.55266e-5f, -8.71758e-4f);
    p = fmaf(s, p, 9.45198e-3f);
    p = fmaf(s, p, -6.62128e-2f);
    p = fmaf(s, p, 0.3989423f);
    return x * fmaf(tc, p, 0.5f);
}
// sum across the 16-lane DPP row (row_ror 1/2/4/8: all lanes get the total)
__device__ __forceinline__ float rowsum16(float x) {
    x += __builtin_bit_cast(float, __builtin_amdgcn_update_dpp(0, __builtin_bit_cast(int, x), 0x121, 0xf, 0xf, false));
    x += __builtin_bit_cast(float, __builtin_amdgcn_update_dpp(0, __builtin_bit_cast(int, x), 0x122, 0xf, 0xf, false));
    x += __builtin_bit_cast(float, __builtin_amdgcn_update_dpp(0, __builtin_bit_cast(int, x), 0x124, 0xf, 0xf, false));
    x += __builtin_bit_cast(float, __builtin_amdgcn_update_dpp(0, __builtin_bit_cast(int, x), 0x128, 0xf, 0xf, false));
    return x;
}

__device__ __forceinline__ short f2h(float x) {
    return __builtin_bit_cast(short, (_Float16)x);
}

// ws layout: shorts(f16) tiWF[0,6144) toWF[6144,12288) ciWF[12288,36864) coWF[36864,61440)
//            then fp32 W2F[4096] at short index 61440 (unused by scan, kept for layout)
__global__ void lno_prep(const float* __restrict__ tiW, const float* __restrict__ toW,
                         const float* __restrict__ ciW, const float* __restrict__ coW,
                         const float* __restrict__ physW2, short* __restrict__ wsf) {
    int id = blockIdx.x * 256 + threadIdx.x;  // 0..65535
    if (id < 6144) {            // A1: m=th, k=ld
        int j = id & 7, lane = (id >> 3) & 63, g = id >> 9;
        int il = g >> 2, u = g & 3;
        int m = u * 16 + (lane & 15), k = (lane >> 4) * 8 + j;
        wsf[id] = f2h(tiW[il * 2048 + k * 64 + m]);
    } else if (id < 12288) {    // A2: m=ld, k=th
        int t = id - 6144;
        int j = t & 7, lane = (t >> 3) & 63, g = t >> 9;
        int il = g >> 2, mt2 = (g >> 1) & 1, ks = g & 1;
        int m = mt2 * 16 + (lane & 15), k = ks * 32 + (lane >> 4) * 8 + j;
        wsf[id] = f2h(toW[il * 2048 + k * 32 + m]);
    } else if (id < 36864) {    // A3: m=ch, k=w
        int t = id - 12288;
        int j = t & 7, lane = (t >> 3) & 63, g = t >> 9;
        int il = g >> 4, mtc = (g >> 1) & 7, ks = g & 1;
        int m = mtc * 16 + (lane & 15), k = ks * 32 + (lane >> 4) * 8 + j;
        wsf[id] = f2h(ciW[il * 8192 + k * 128 + m]);
    } else if (id < 61440) {    // B4: k=ch, n=w
        int t = id - 36864;
        int j = t & 7, lane = (t >> 3) & 63, g = t >> 9;
        int il = g >> 4, nt = (g >> 2) & 3, ks = g & 3;
        int n = nt * 16 + (lane & 15), k = ks * 32 + (lane >> 4) * 8 + j;
        wsf[id] = f2h(coW[il * 8192 + k * 64 + n]);
    } else if (id < 65536) {    // W2F fp32 [w][k]
        int t = id - 61440;
        int w = t >> 6, k = t & 63;
        ((float*)(wsf + 61440))[t] = physW2[k * 64 + w];
    }
}

// phys MLP pre-pass: p[b,t,w] = gelu(phys@W1+b1)@W2+b2, stored f16 in d_out's
// [b,t] 128B slot, permuted so scan lane (q,c) reads its 4 values {w=nt*16+c}
// as one 8B load: slot j = (w&15)*4 + (w>>4).
__global__ void lno_phys(const float* __restrict__ phys, const float* __restrict__ physW1,
                         const float* __restrict__ physb1, const float* __restrict__ physW2,
                         const float* __restrict__ physb2, short* __restrict__ pout) {
    __shared__ float hsh[4][64];
    const int lane = threadIdx.x & 63, wv = threadIdx.x >> 6;
    const size_t bt = (size_t)blockIdx.x * 4 + wv;   // < 2048*256
    const float* pt = phys + bt * 8;
    float4 px0 = *(const float4*)pt, px1 = *(const float4*)(pt + 4);
    float a = physb1[lane];
    a = fmaf(px0.x, physW1[0 * 64 + lane], a);
    a = fmaf(px0.y, physW1[1 * 64 + lane], a);
    a = fmaf(px0.z, physW1[2 * 64 + lane], a);
    a = fmaf(px0.w, physW1[3 * 64 + lane], a);
    a = fmaf(px1.x, physW1[4 * 64 + lane], a);
    a = fmaf(px1.y, physW1[5 * 64 + lane], a);
    a = fmaf(px1.z, physW1[6 * 64 + lane], a);
    a = fmaf(px1.w, physW1[7 * 64 + lane], a);
    hsh[wv][lane] = gelu_f(a);
    float acc = physb2[lane];
#pragma unroll
    for (int k = 0; k < 64; ++k) acc = fmaf(hsh[wv][k], physW2[k * 64 + lane], acc);
    pout[bt * 64 + (lane & 15) * 4 + (lane >> 4)] = f2h(acc);
}

// block = 256 thr = 4 waves; each wave runs TWO independent batches (streams
// s=0,1) phase-interleaved. All weights+biases in LDS (staged once); no
// barriers in the t loop. pbuf and out alias (both d_out): p[b,t] is read at
// step-t start, out[b,t] written at step-t end by the same wave -> no hazard.
__global__ __launch_bounds__(256, 1) void lno_scan(
    const float* __restrict__ latents, const float* __restrict__ pos_emb,
    const float* __restrict__ tokW,    const float* __restrict__ tokb,
    const float* __restrict__ tn_g,    const float* __restrict__ tn_b,
    const float* __restrict__ tib,     const float* __restrict__ tob,
    const float* __restrict__ cn_g,    const float* __restrict__ cn_b,
    const float* __restrict__ cib,     const float* __restrict__ cob,
    const float* __restrict__ hn_g,    const float* __restrict__ hn_b,
    const float* __restrict__ headW,   const float* __restrict__ headb,
    const short* __restrict__ wsf,     const short* pbuf, float* out)
{
    __shared__ __align__(16) short wAll[61440];   // tiL[0,6144) toL[..12288) ciL[..36864) coL[..61440)
    __shared__ __align__(16) short scr[4][4096];  // per-wave scratch, 2048 shorts per stream
    __shared__ __align__(16) float biasL[1632];   // tib[0) tob[192) cib[288) tn_g[672) tn_b[864)
                                                  // cn_g[1056) cn_b[1248) cob[1440)

    const int tid = threadIdx.x, lane = tid & 63, wv = tid >> 6;
    const int q = lane >> 4, c = lane & 15;
    const int bb = (blockIdx.x * 4 + wv) * 2;     // batches bb, bb+1

    const short* tiL = wAll;
    const short* toL = wAll + 6144;
    const short* ciL = wAll + 12288;
    const short* coL = wAll + 36864;
    short* const scp[2] = { &scr[wv][0], &scr[wv][2048] };

    // ---- one-shot weight stage: 120 chunks of 1KB, wave wv does 30 ----
    {
        const unsigned int* src = (const unsigned int*)wsf;
#pragma unroll
        for (int i = 0; i < 30; ++i) {
            const int cid = wv * 30 + i;
            __builtin_amdgcn_global_load_lds(src + cid * 256 + lane * 4,
                                             (unsigned int*)&wAll[cid * 512], 16, 0, 0);
        }
    }
    // ---- one-shot bias/LN-param stage ----
    for (int i = tid; i < 192; i += 256) {
        biasL[i] = tib[i];
        biasL[672 + i]  = tn_g[i];
        biasL[864 + i]  = tn_b[i];
        biasL[1056 + i] = cn_g[i];
        biasL[1248 + i] = cn_b[i];
        biasL[1440 + i] = cob[i];
    }
    for (int i = tid; i < 96;  i += 256) biasL[192 + i] = tob[i];
    for (int i = tid; i < 384; i += 256) biasL[288 + i] = cib[i];

    // ---- hoisted per-lane constants (shared by both streams) ----
    float tokw_r[4], tokb_r[4], gh_r[4];
#pragma unroll
    for (int nt = 0; nt < 4; ++nt) {
        tokw_r[nt] = tokW[nt * 16 + c];
        tokb_r[nt] = tokb[nt * 16 + c];
        gh_r[nt]   = hn_g[nt * 16 + c] * headW[nt * 16 + c];
    }
    float bhp = 0.f;
#pragma unroll
    for (int nt = 0; nt < 4; ++nt) bhp = fmaf(hn_b[nt * 16 + c], headW[nt * 16 + c], bhp);
    const float bh = rowsum16(bhp) + headb[0];

    f32x4 pe4[2][4];
#pragma unroll
    for (int mt = 0; mt < 2; ++mt)
#pragma unroll
        for (int nt = 0; nt < 4; ++nt)
#pragma unroll
            for (int r = 0; r < 4; ++r)
                pe4[mt][nt][r] = pos_emb[(mt * 16 + q * 4 + r) * 64 + nt * 16 + c];

    f32x4 cur8[2][2];
#pragma unroll
    for (int s = 0; s < 2; ++s)
#pragma unroll
        for (int mt = 0; mt < 2; ++mt)
            cur8[s][mt] = *(const f32x4*)(latents + (bb + s) * 32 + mt * 16 + q * 4);

    f32x4 tok[2][2][4];   // [stream][mt][nt]

    __syncthreads();  // weights (vmcnt drained) + biasL ready; last barrier.

    // per-stream stats: packed pre-reduction, scalar DPP reduce
    auto stats1 = [&](const f32x4 (&tk)[2][4], f32x4 (&mean)[2], f32x4 (&rsig)[2]) {
#pragma unroll
        for (int mt = 0; mt < 2; ++mt) {
            f32x4 s4 = (tk[mt][0] + tk[mt][1]) + (tk[mt][2] + tk[mt][3]);
            f32x4 q4 = tk[mt][0] * tk[mt][0];
            q4 = __builtin_elementwise_fma(tk[mt][1], tk[mt][1], q4);
            q4 = __builtin_elementwise_fma(tk[mt][2], tk[mt][2], q4);
            q4 = __builtin_elementwise_fma(tk[mt][3], tk[mt][3], q4);
#pragma unroll
            for (int r = 0; r < 4; ++r) {
                float ss = rowsum16(s4[r]);
                float qq = rowsum16(q4[r]);
                float m = ss * 0.015625f;
                float v = fmaf(-m, m, qq * 0.015625f);
                mean[mt][r] = m;
                rsig[mt][r] = __builtin_amdgcn_rsqf(v + 1e-5f);
            }
        }
    };

    // p prefetch (one step ahead), per stream
    const short* pb0 = pbuf + (size_t)(bb + 0) * Tt * 64 + c * 4;
    const short* pb1 = pbuf + (size_t)(bb + 1) * Tt * 64 + c * 4;
    h16x4 pvc0 = *(const h16x4*)pb0;
    h16x4 pvc1 = *(const h16x4*)pb1;

#pragma unroll 1
    for (int t = 0; t < Tt; ++t) {
        const h16x4 pv[2] = { pvc0, pvc1 };
        if (t + 1 < Tt) {
            pvc0 = *(const h16x4*)(pb0 + (t + 1) * 64);
            pvc1 = *(const h16x4*)(pb1 + (t + 1) * 64);
        }

        // ======== token init (both streams) ========
#pragma unroll
        for (int s = 0; s < 2; ++s)
#pragma unroll
            for (int nt = 0; nt < 4; ++nt) {
                const f32x4 bp = f4s(tokb_r[nt] + (float)pv[s][nt]);
                const f32x4 tw = f4s(tokw_r[nt]);
#pragma unroll
                for (int mt = 0; mt < 2; ++mt)
                    tok[s][mt][nt] = __builtin_elementwise_fma(cur8[s][mt], tw, pe4[mt][nt] + bp);
            }

#pragma unroll 1
        for (int il = 0; il < NL; ++il) {
            // ======== token mixing ========
            f32x4 mean[2][2], rsig[2][2];
#pragma unroll
            for (int s = 0; s < 2; ++s) stats1(tok[s], mean[s], rsig[s]);
            float tng[4], tnb[4];
#pragma unroll
            for (int nt = 0; nt < 4; ++nt) {
                tng[nt] = biasL[672 + il * 64 + nt * 16 + c];
                tnb[nt] = biasL[864 + il * 64 + nt * 16 + c];
            }
            // LN1 -> scratch (y B-frags), per stream
#pragma unroll
            for (int s = 0; s < 2; ++s)
#pragma unroll
                for (int mt = 0; mt < 2; ++mt)
#pragma unroll
                    for (int nt = 0; nt < 4; ++nt) {
                        f32x4 y = __builtin_elementwise_fma((tok[s][mt][nt] - mean[s][mt]) * rsig[s][mt],
                                                            f4s(tng[nt]), f4s(tnb[nt]));
                        st4h(&scp[s][(nt * 64 + (mt * 2 + (q >> 1)) * 16 + c) * 8 + (q & 1) * 4],
                             pkrtz(y[0], y[1]), pkrtz(y[2], y[3]));
                    }
            h16x8 yfrag[2][4];
#pragma unroll
            for (int s = 0; s < 2; ++s)
#pragma unroll
                for (int nt = 0; nt < 4; ++nt)
                    yfrag[s][nt] = *(const h16x8*)&scp[s][(nt * 64 + lane) * 8];

            // pre-add tob (per-row); mm2 then accumulates in place
#pragma unroll
            for (int mt = 0; mt < 2; ++mt) {
                const f32x4 tb = *(const f32x4*)&biasL[192 + il * 32 + mt * 16 + q * 4];
#pragma unroll
                for (int s = 0; s < 2; ++s)
#pragma unroll
                    for (int nt = 0; nt < 4; ++nt) tok[s][mt][nt] += tb;
            }
            // mm1 (gelu -> scratch) + mm2, by K-half h; weight frags shared
#pragma unroll
            for (int h = 0; h < 2; ++h) {
#pragma unroll
                for (int uu = 0; uu < 2; ++uu) {
                    const int uw = h * 2 + uu;
                    const h16x8 a1 = *(const h16x8*)(tiL + ((il * 4 + uw) * 64 + lane) * 8);
                    const f32x4 bi = *(const f32x4*)&biasL[il * 64 + uw * 16 + q * 4];
#pragma unroll
                    for (int s = 0; s < 2; ++s)
#pragma unroll
                        for (int nt = 0; nt < 4; ++nt) {
                            f32x4 acc = MFMA16(a1, yfrag[s][nt], bi);
                            st4h(&scp[s][(nt * 64 + (uu * 2 + (q >> 1)) * 16 + c) * 8 + (q & 1) * 4],
                                 gelu_pk(pkrtz(acc[0], acc[1])), gelu_pk(pkrtz(acc[2], acc[3])));
                        }
                }
                h16x8 hf[2][4];
#pragma unroll
                for (int s = 0; s < 2; ++s)
#pragma unroll
                    for (int nt = 0; nt < 4; ++nt)
                        hf[s][nt] = *(const h16x8*)&scp[s][(nt * 64 + lane) * 8];
#pragma unroll
                for (int mt = 0; mt < 2; ++mt) {
                    const h16x8 a2 = *(const h16x8*)(toL + ((il * 4 + mt * 2 + h) * 64 + lane) * 8);
#pragma unroll
                    for (int s = 0; s < 2; ++s)
#pragma unroll
                        for (int nt = 0; nt < 4; ++nt)
                            tok[s][mt][nt] = MFMA16(a2, hf[s][nt], tok[s][mt][nt]);
                }
            }

            // ======== channel mixing ========
#pragma unroll
            for (int s = 0; s < 2; ++s) stats1(tok[s], mean[s], rsig[s]);
            float cng[4], cnb[4];
#pragma unroll
            for (int nt = 0; nt < 4; ++nt) {
                cng[nt] = biasL[1056 + il * 64 + nt * 16 + c];
                cnb[nt] = biasL[1248 + il * 64 + nt * 16 + c];
            }
            // LN2 -> scratch (B3 frags, swizzled slots), per stream
#pragma unroll
            for (int s = 0; s < 2; ++s)
#pragma unroll
                for (int mt = 0; mt < 2; ++mt)
#pragma unroll
                    for (int nt = 0; nt < 4; ++nt) {
                        f32x4 v4 = __builtin_elementwise_fma((tok[s][mt][nt] - mean[s][mt]) * rsig[s][mt],
                                                             f4s(cng[nt]), f4s(cnb[nt]));
#pragma unroll
                        for (int r = 0; r < 4; ++r)
                            scp[s][(mt * 2 + (nt >> 1)) * 512 +
                                   (q * 2 + (c >> 3) + 16 * r + 8 * (nt & 1)) * 8 + (c & 7)] = f2h(v4[r]);
                    }
            h16x8 b3[2][4];
            {
                const int lp = ((c >> 2) * 2 + (q & 1)) + 8 * ((c & 3) * 2 + (q >> 1));
#pragma unroll
                for (int s = 0; s < 2; ++s)
#pragma unroll
                    for (int F = 0; F < 4; ++F)
                        b3[s][F] = *(const h16x8*)&scp[s][F * 512 + lp * 8];
            }
            // pre-add cob (per-col); mm4 accumulates in place
#pragma unroll
            for (int nt = 0; nt < 4; ++nt) {
                const f32x4 cv = f4s(biasL[1440 + il * 64 + nt * 16 + c]);
#pragma unroll
                for (int s = 0; s < 2; ++s)
#pragma unroll
                    for (int mt = 0; mt < 2; ++mt) tok[s][mt][nt] += cv;
            }

            // mm3 (gelu -> scratch) + mm4, by ch-half hh; weight frags shared
#pragma unroll
            for (int hh = 0; hh < 2; ++hh) {
#pragma unroll
                for (int mm = 0; mm < 4; ++mm) {
                    const int mtc = hh * 4 + mm;
                    const h16x8 a30 = *(const h16x8*)(ciL + il * 8192 + (mtc * 2 + 0) * 512 + lane * 8);
                    const h16x8 a31 = *(const h16x8*)(ciL + il * 8192 + (mtc * 2 + 1) * 512 + lane * 8);
                    const f32x4 bi3 = *(const f32x4*)&biasL[288 + il * 128 + mtc * 16 + q * 4];
#pragma unroll
                    for (int s = 0; s < 2; ++s)
#pragma unroll
                        for (int ntl = 0; ntl < 2; ++ntl) {
                            f32x4 acc = MFMA16(a30, b3[s][ntl * 2 + 0], bi3);
                            acc = MFMA16(a31, b3[s][ntl * 2 + 1], acc);
                            st4h(&scp[s][((ntl * 2 + ((mtc >> 1) & 1)) * 64 +
                                          ((mtc & 1) * 2 + (q >> 1)) * 16 + c) * 8 + (q & 1) * 4],
                                 gelu_pk(pkrtz(acc[0], acc[1])), gelu_pk(pkrtz(acc[2], acc[3])));
                        }
                }
                h16x8 a4[2][2][2];
#pragma unroll
                for (int s = 0; s < 2; ++s)
#pragma unroll
                    for (int mt = 0; mt < 2; ++mt)
#pragma unroll
                        for (int kk = 0; kk < 2; ++kk)
                            a4[s][mt][kk] = *(const h16x8*)&scp[s][((mt * 2 + kk) * 64 + lane) * 8];
#pragma unroll
                for (int nt = 0; nt < 4; ++nt) {
                    const h16x8 b40 = *(const h16x8*)(coL + il * 8192 + (nt * 4 + hh * 2 + 0) * 512 + lane * 8);
                    const h16x8 b41 = *(const h16x8*)(coL + il * 8192 + (nt * 4 + hh * 2 + 1) * 512 + lane * 8);
#pragma unroll
                    for (int s = 0; s < 2; ++s)
#pragma unroll
                        for (int mt = 0; mt < 2; ++mt) {
                            tok[s][mt][nt] = MFMA16(a4[s][mt][0], b40, tok[s][mt][nt]);
                            tok[s][mt][nt] = MFMA16(a4[s][mt][1], b41, tok[s][mt][nt]);
                        }
                }
            }
        }  // il

        // ======== head (both streams) ========
        {
            f32x4 mean[2][2], rsig[2][2];
#pragma unroll
            for (int s = 0; s < 2; ++s) stats1(tok[s], mean[s], rsig[s]);
#pragma unroll
            for (int s = 0; s < 2; ++s)
#pragma unroll
                for (int mt = 0; mt < 2; ++mt) {
                    f32x4 l4 = (tok[s][mt][0] - mean[s][mt]) * f4s(gh_r[0]);
                    l4 = __builtin_elementwise_fma(tok[s][mt][1] - mean[s][mt], f4s(gh_r[1]), l4);
                    l4 = __builtin_elementwise_fma(tok[s][mt][2] - mean[s][mt], f4s(gh_r[2]), l4);
                    l4 = __builtin_elementwise_fma(tok[s][mt][3] - mean[s][mt], f4s(gh_r[3]), l4);
                    f32x4 ls;
#pragma unroll
                    for (int r = 0; r < 4; ++r) ls[r] = rowsum16(l4[r]);
                    f32x4 nv = cur8[s][mt] + __builtin_elementwise_fma(rsig[s][mt], ls, f4s(bh));
                    nv = __builtin_elementwise_min(__builtin_elementwise_max(nv, f4s(0.f)), f4s(1.f));
                    cur8[s][mt] = nv;
                }
            if (c == 0) {
#pragma unroll
                for (int s = 0; s < 2; ++s) {
                    float* op = out + ((size_t)(bb + s) * Tt + t) * 32 + q * 4;
                    *(f32x4*)(op) = cur8[s][0];
                    *(f32x4*)(op + 16) = cur8[s][1];
                }
            }
        }
    }  // t
}
}  // namespace

extern "C" void kernel_launch(void* const* d_in, const int* in_sizes, int n_in,
                              void* d_out, int out_size, void* d_ws, size_t ws_size,
                              hipStream_t stream) {
    (void)in_sizes; (void)n_in; (void)ws_size; (void)out_size;
    const float* phys    = (const float*)d_in[0];
    const float* latents = (const float*)d_in[1];
    const float* pos_emb = (const float*)d_in[2];
    const float* tokW    = (const float*)d_in[3];
    const float* tokb    = (const float*)d_in[4];
    const float* physW1  = (const float*)d_in[5];
    const float* physb1  = (const float*)d_in[6];
    const float* physW2  = (const float*)d_in[7];
    const float* physb2  = (const float*)d_in[8];
    const float* tn_g    = (const float*)d_in[9];
    const float* tn_b    = (const float*)d_in[10];
    const float* tiW     = (const float*)d_in[11];
    const float* tib     = (const float*)d_in[12];
    const float* toW     = (const float*)d_in[13];
    const float* tob     = (const float*)d_in[14];
    const float* cn_g    = (const float*)d_in[15];
    const float* cn_b    = (const float*)d_in[16];
    const float* ciW     = (const float*)d_in[17];
    const float* cib     = (const float*)d_in[18];
    const float* coW     = (const float*)d_in[19];
    const float* cob     = (const float*)d_in[20];
    const float* hn_g    = (const float*)d_in[21];
    const float* hn_b    = (const float*)d_in[22];
    const float* headW   = (const float*)d_in[23];
    const float* headb   = (const float*)d_in[24];

    lno_prep<<<dim3(256), dim3(256), 0, stream>>>(tiW, toW, ciW, coW, physW2, (short*)d_ws);
    // p pre-pass into d_out (B*T = 524288 waves; 4 waves/block)
    lno_phys<<<dim3(131072), dim3(256), 0, stream>>>(phys, physW1, physb1, physW2, physb2,
                                                     (short*)d_out);
    // scan: 256 blocks (1/CU), 4 waves/block, 2 batches/wave
    lno_scan<<<dim3(256), dim3(256), 0, stream>>>(
        latents, pos_emb, tokW, tokb, tn_g, tn_b, tib, tob,
        cn_g, cn_b, cib, cob, hn_g, hn_b, headW, headb,
        (const short*)d_ws, (const short*)d_out, (float*)d_out);
}

// Round 7
// 7246.268 us; speedup vs baseline: 1.1076x; 1.1076x over previous
//
#include <hip/hip_runtime.h>
#include <math.h>

// Round 10b: compile-fix resubmit of round 10 (builtin is
// __builtin_amdgcn_mfma_f32_16x16x16f16 on gfx950 -- no underscore before f16).
// Half-batch wave teams -> 4 waves/SIMD with LDS-flag pairwise sync.
//  - r9 post-mortem: dual-stream ILP regressed 22%: lgkmcnt is ONE in-order
//    queue per wave; interleaved streams serialize through it. LDS latency
//    hiding needs separate WAVES.
//  - r10: block = 1024 thr = 16 waves = 8 teams x 2 waves, grid 256 (1/CU).
//    Team splits one batch by latent-row halves (mt = sb). Channel mixing,
//    stats, LN, head: wave-local. Token mixing exchanges y/h via a 4KB team
//    buffer with acquire/release LDS flags (NO block barriers in the loop ->
//    teams stay decoupled; each SIMD holds 4 waves of 4 different teams).
//  - token-mix uses mfma 16x16x16 K-chunks: own-half LN1(y)/gelu(h) C-pieces
//    ARE the x16 B-fragments (j==r) -> own-half LDS relayout eliminated;
//    only partner halves cross LDS. tiW/toW prepped as x16 frags.
//  - launch_bounds(1024,4): 128-VGPR cap (state ~110). LDS 162.4KB.
//
// Fragment layouts (gfx950, verified r2-r9):
//   x32: A[m=lane&15][k=8q+j], B[k=8q+j][n=lane&15]
//   x16: A[m=lane&15][k=4q+j], B[k=4q+j][n=lane&15]
//   C (both): col=lane&15, row=4q+reg.

namespace {
constexpr int Tt = 256, NL = 3;

typedef float    f32x4 __attribute__((ext_vector_type(4)));
typedef _Float16 half2 __attribute__((ext_vector_type(2)));
typedef _Float16 h16x4 __attribute__((ext_vector_type(4)));
typedef _Float16 h16x8 __attribute__((ext_vector_type(8)));

#define MFMA32(a, b, c) __builtin_amdgcn_mfma_f32_16x16x32_f16((a), (b), (c), 0, 0, 0)
#define MFMA16(a, b, c) __builtin_amdgcn_mfma_f32_16x16x16f16((a), (b), (c), 0, 0, 0)
#define REL(p, v) __hip_atomic_store((p), (v), __ATOMIC_RELEASE, __HIP_MEMORY_SCOPE_WORKGROUP)
#define ACQ(p) __hip_atomic_load((p), __ATOMIC_ACQUIRE, __HIP_MEMORY_SCOPE_WORKGROUP)

__device__ __forceinline__ half2 h2c(float v) { return (half2)((_Float16)v); }
__device__ __forceinline__ f32x4 f4s(float v) { return (f32x4)v; }
__device__ __forceinline__ half2 pkrtz(float a, float b) {
    return __builtin_bit_cast(half2, __builtin_amdgcn_cvt_pkrtz(a, b));
}
__device__ __forceinline__ void st4h(short* p, half2 a, half2 b) {
    uint2 v;
    v.x = __builtin_bit_cast(unsigned int, a);
    v.y = __builtin_bit_cast(unsigned int, b);
    *(uint2*)p = v;
}
__device__ __forceinline__ h16x4 h4(half2 a, half2 b) {
    h16x4 v; v[0] = a[0]; v[1] = a[1]; v[2] = b[0]; v[3] = b[1]; return v;
}
__device__ __forceinline__ half2 lo2(h16x4 v) { half2 r; r[0] = v[0]; r[1] = v[1]; return r; }
__device__ __forceinline__ half2 hi2(h16x4 v) { half2 r; r[0] = v[2]; r[1] = v[3]; return r; }
// packed f16 GELU, no transcendentals (unchanged numerics from r5-r9)
__device__ __forceinline__ half2 gelu_pk(half2 x) {
    half2 tc = __builtin_elementwise_min(__builtin_elementwise_max(x, h2c(-3.0f)), h2c(3.0f));
    half2 s = (tc * tc) * h2c(0.125f);
    half2 p = s * h2c(0.1455169f) + h2c(-0.446340f);
    p = s * p + h2c(0.604927f);
    p = s * p + h2c(-0.529702f);
    p = s * p + h2c(0.3989423f);
    return x * (h2c(0.5f) + tc * p);
}
__device__ __forceinline__ float gelu_f(float x) {
    float tc = fminf(fmaxf(x, -3.f), 3.f);
    float s = tc * tc;
    float p = fmaf(s, 3.55266e-5f, -8.71758e-4f);
    p = fmaf(s, p, 9.45198e-3f);
    p = fmaf(s, p, -6.62128e-2f);
    p = fmaf(s, p, 0.3989423f);
    return x * fmaf(tc, p, 0.5f);
}
// sum across the 16-lane DPP row (all lanes get the total)
__device__ __forceinline__ float rowsum16(float x) {
    x += __builtin_bit_cast(float, __builtin_amdgcn_update_dpp(0, __builtin_bit_cast(int, x), 0x121, 0xf, 0xf, false));
    x += __builtin_bit_cast(float, __builtin_amdgcn_update_dpp(0, __builtin_bit_cast(int, x), 0x122, 0xf, 0xf, false));
    x += __builtin_bit_cast(float, __builtin_amdgcn_update_dpp(0, __builtin_bit_cast(int, x), 0x124, 0xf, 0xf, false));
    x += __builtin_bit_cast(float, __builtin_amdgcn_update_dpp(0, __builtin_bit_cast(int, x), 0x128, 0xf, 0xf, false));
    return x;
}
__device__ __forceinline__ short f2h(float x) {
    return __builtin_bit_cast(short, (_Float16)x);
}

// ws layout (shorts/f16):
//   A1 x16 frags [0,6144): tiles ((il*4+u)*2+kc)*256, elem lane*4+j
//       = tiW[il][ld=16kc+4q+j][th=16u+c]
//   A2 x16 frags [6144,12288): tiles ((il*2+sb)*4+kc)*256
//       = toW[il][th=16kc+4q+j][ld=16sb+c]
//   A3 x32 frags [12288,36864): as r5-r9 (ciW)
//   B4 x32 frags [36864,61440): as r5-r9 (coW)
//   W2F fp32 tail kept for layout (unused by scan)
__global__ void lno_prep(const float* __restrict__ tiW, const float* __restrict__ toW,
                         const float* __restrict__ ciW, const float* __restrict__ coW,
                         const float* __restrict__ physW2, short* __restrict__ wsf) {
    int id = blockIdx.x * 256 + threadIdx.x;  // 0..65535
    if (id < 6144) {            // A1 x16: m=th, k=ld-chunk
        int e = id & 255, tile = id >> 8;           // 24 tiles
        int lane = e >> 2, j = e & 3;
        int q = lane >> 4, cc = lane & 15;
        int kc = tile & 1, u = (tile >> 1) & 3, il = tile >> 3;
        wsf[id] = f2h(tiW[il * 2048 + (16 * kc + 4 * q + j) * 64 + 16 * u + cc]);
    } else if (id < 12288) {    // A2 x16: m=ld-half, k=th-chunk
        int t = id - 6144;
        int e = t & 255, tile = t >> 8;             // 24 tiles
        int lane = e >> 2, j = e & 3;
        int q = lane >> 4, cc = lane & 15;
        int kc = tile & 3, sb = (tile >> 2) & 1, il = tile >> 3;
        wsf[id] = f2h(toW[il * 2048 + (16 * kc + 4 * q + j) * 32 + 16 * sb + cc]);
    } else if (id < 36864) {    // A3 x32: m=ch, k=w  (unchanged)
        int t = id - 12288;
        int j = t & 7, lane = (t >> 3) & 63, g = t >> 9;
        int il = g >> 4, mtc = (g >> 1) & 7, ks = g & 1;
        int m = mtc * 16 + (lane & 15), k = ks * 32 + (lane >> 4) * 8 + j;
        wsf[id] = f2h(ciW[il * 8192 + k * 128 + m]);
    } else if (id < 61440) {    // B4 x32: k=ch, n=w  (unchanged)
        int t = id - 36864;
        int j = t & 7, lane = (t >> 3) & 63, g = t >> 9;
        int il = g >> 4, nt = (g >> 2) & 3, ks = g & 3;
        int n = nt * 16 + (lane & 15), k = ks * 32 + (lane >> 4) * 8 + j;
        wsf[id] = f2h(coW[il * 8192 + k * 64 + n]);
    } else if (id < 65536) {
        int t = id - 61440;
        int w = t >> 6, k = t & 63;
        ((float*)(wsf + 61440))[t] = physW2[k * 64 + w];
    }
}

// phys MLP pre-pass (unchanged): p stored f16 in d_out's [b,t] 128B slot,
// permuted so scan lane (q,c) reads its 4 values {w=nt*16+c} as one 8B load.
__global__ void lno_phys(const float* __restrict__ phys, const float* __restrict__ physW1,
                         const float* __restrict__ physb1, const float* __restrict__ physW2,
                         const float* __restrict__ physb2, short* __restrict__ pout) {
    __shared__ float hsh[4][64];
    const int lane = threadIdx.x & 63, wv = threadIdx.x >> 6;
    const size_t bt = (size_t)blockIdx.x * 4 + wv;
    const float* pt = phys + bt * 8;
    float4 px0 = *(const float4*)pt, px1 = *(const float4*)(pt + 4);
    float a = physb1[lane];
    a = fmaf(px0.x, physW1[0 * 64 + lane], a);
    a = fmaf(px0.y, physW1[1 * 64 + lane], a);
    a = fmaf(px0.z, physW1[2 * 64 + lane], a);
    a = fmaf(px0.w, physW1[3 * 64 + lane], a);
    a = fmaf(px1.x, physW1[4 * 64 + lane], a);
    a = fmaf(px1.y, physW1[5 * 64 + lane], a);
    a = fmaf(px1.z, physW1[6 * 64 + lane], a);
    a = fmaf(px1.w, physW1[7 * 64 + lane], a);
    hsh[wv][lane] = gelu_f(a);
    float acc = physb2[lane];
#pragma unroll
    for (int k = 0; k < 64; ++k) acc = fmaf(hsh[wv][k], physW2[k * 64 + lane], acc);
    pout[bt * 64 + (lane & 15) * 4 + (lane >> 4)] = f2h(acc);
}

// 1024 thr = 16 waves = 8 teams x 2 waves; 1 block/CU. Flag protocol per layer
// (g = t*3+il+1): F[0/1]=y-ready(sb), F[5]=y0-consumed, F[2/3]=h0/h1-ready,
// F[4]=h1-consumed. Verified acyclic; team buf reuse ordered by flags +
// per-wave DS in-order completion. pbuf/out alias d_out (read-before-write
// per wave as in r7-r9).
__global__ __launch_bounds__(1024, 4) void lno_scan(
    const float* __restrict__ latents, const float* __restrict__ pos_emb,
    const float* __restrict__ tokW,    const float* __restrict__ tokb,
    const float* __restrict__ tn_g,    const float* __restrict__ tn_b,
    const float* __restrict__ tib,     const float* __restrict__ tob,
    const float* __restrict__ cn_g,    const float* __restrict__ cn_b,
    const float* __restrict__ cib,     const float* __restrict__ cob,
    const float* __restrict__ hn_g,    const float* __restrict__ hn_b,
    const float* __restrict__ headW,   const float* __restrict__ headb,
    const short* __restrict__ wsf,     const short* pbuf, float* out)
{
    __shared__ __align__(16) short wAll[61440];   // A1|A2|A3|B4
    __shared__ __align__(16) short tbuf[8][2048]; // 4KB per team
    __shared__ __align__(16) float biasL[1632];   // tib[0) tob[192) cib[288) tn_g[672)
                                                  // tn_b[864) cn_g[1056) cn_b[1248) cob[1440)
    __shared__ int flags[8][8];

    const int tid = threadIdx.x, lane = tid & 63, wv = tid >> 6;
    const int sb = wv & 1, tm = wv >> 1, pn = sb ^ 1;
    const int q = lane >> 4, c = lane & 15;
    const int b = blockIdx.x * 8 + tm;
    short* buf = tbuf[tm];
    short* mysc = buf + sb * 1024;   // wave-local channel scratch (== own y region)
    int* F = flags[tm];

    const short* A1L = wAll;
    const short* A2L = wAll + 6144;
    const short* A3L = wAll + 12288;
    const short* B4L = wAll + 36864;

    // ---- one-shot weight stage: 120 chunks of 1KB; waves 0..14 do 8 each ----
    if (wv < 15) {
        const unsigned int* src = (const unsigned int*)wsf;
#pragma unroll
        for (int i = 0; i < 8; ++i) {
            const int cid = wv * 8 + i;
            __builtin_amdgcn_global_load_lds(src + cid * 256 + lane * 4,
                                             (unsigned int*)&wAll[cid * 512], 16, 0, 0);
        }
    }
    // ---- one-shot bias/LN-param stage ----
    for (int i = tid; i < 192; i += 1024) {
        biasL[i] = tib[i];
        biasL[672 + i]  = tn_g[i];
        biasL[864 + i]  = tn_b[i];
        biasL[1056 + i] = cn_g[i];
        biasL[1248 + i] = cn_b[i];
        biasL[1440 + i] = cob[i];
    }
    for (int i = tid; i < 96;  i += 1024) biasL[192 + i] = tob[i];
    for (int i = tid; i < 384; i += 1024) biasL[288 + i] = cib[i];
    if (tid < 64) ((int*)flags)[tid] = 0;

    // ---- hoisted per-lane constants ----
    float tokw_r[4], tokb_r[4], gh_r[4];
#pragma unroll
    for (int nt = 0; nt < 4; ++nt) {
        tokw_r[nt] = tokW[nt * 16 + c];
        tokb_r[nt] = tokb[nt * 16 + c];
        gh_r[nt]   = hn_g[nt * 16 + c] * headW[nt * 16 + c];
    }
    float bhp = 0.f;
#pragma unroll
    for (int nt = 0; nt < 4; ++nt) bhp = fmaf(hn_b[nt * 16 + c], headW[nt * 16 + c], bhp);
    const float bh = rowsum16(bhp) + headb[0];

    f32x4 pe4[4];   // own half rows
#pragma unroll
    for (int nt = 0; nt < 4; ++nt)
#pragma unroll
        for (int r = 0; r < 4; ++r)
            pe4[nt][r] = pos_emb[(sb * 16 + q * 4 + r) * 64 + nt * 16 + c];

    f32x4 cur = *(const f32x4*)(latents + b * 32 + sb * 16 + q * 4);
    f32x4 tok[4];

    __syncthreads();  // weights (vmcnt drained) + biasL + flags ready; only barrier.

    auto stats = [&](f32x4& mean, f32x4& rsig) {
        f32x4 s4 = (tok[0] + tok[1]) + (tok[2] + tok[3]);
        f32x4 q4 = tok[0] * tok[0];
        q4 = __builtin_elementwise_fma(tok[1], tok[1], q4);
        q4 = __builtin_elementwise_fma(tok[2], tok[2], q4);
        q4 = __builtin_elementwise_fma(tok[3], tok[3], q4);
#pragma unroll
        for (int r = 0; r < 4; ++r) {
            float ss = rowsum16(s4[r]);
            float qq = rowsum16(q4[r]);
            float m = ss * 0.015625f;
            float v = fmaf(-m, m, qq * 0.015625f);
            mean[r] = m;
            rsig[r] = __builtin_amdgcn_rsqf(v + 1e-5f);
        }
    };

    const short* pb = pbuf + (size_t)b * Tt * 64 + c * 4;
    h16x4 pvc = *(const h16x4*)pb;

#pragma unroll 1
    for (int t = 0; t < Tt; ++t) {
        const h16x4 pv = pvc;
        if (t + 1 < Tt) pvc = *(const h16x4*)(pb + (t + 1) * 64);

        // ======== token init (own rows) ========
#pragma unroll
        for (int nt = 0; nt < 4; ++nt) {
            const f32x4 bp = f4s(tokb_r[nt] + (float)pv[nt]);
            tok[nt] = __builtin_elementwise_fma(cur, f4s(tokw_r[nt]), pe4[nt] + bp);
        }

#pragma unroll 1
        for (int il = 0; il < NL; ++il) {
            const int g = t * 3 + il + 1;
            // ======== token mixing ========
            f32x4 mean, rsig;
            stats(mean, rsig);
            // LN1 -> own B1-x16 frags (regs) + write to own y region
            h16x4 b1own[4];
#pragma unroll
            for (int nt = 0; nt < 4; ++nt) {
                const float tng = biasL[672 + il * 64 + nt * 16 + c];
                const float tnb = biasL[864 + il * 64 + nt * 16 + c];
                f32x4 y = __builtin_elementwise_fma((tok[nt] - mean) * rsig,
                                                    f4s(tng), f4s(tnb));
                half2 d0 = pkrtz(y[0], y[1]), d1 = pkrtz(y[2], y[3]);
                b1own[nt] = h4(d0, d1);
                st4h(&buf[sb * 1024 + (nt * 64 + lane) * 4], d0, d1);
            }
            if (lane == 0) REL(&F[sb], g);
            // tob pre-add (own rows)
            {
                const f32x4 tb = *(const f32x4*)&biasL[192 + il * 32 + sb * 16 + q * 4];
#pragma unroll
                for (int nt = 0; nt < 4; ++nt) tok[nt] += tb;
            }
            // mm1 pass 1: own ld-chunk (kc = sb), bias as C-in
            f32x4 hacc[2][4];
#pragma unroll
            for (int uu = 0; uu < 2; ++uu) {
                const int u = 2 * sb + uu;
                const h16x4 a1 = *(const h16x4*)(A1L + (((il * 4 + u) * 2) + sb) * 256 + lane * 4);
                const f32x4 bi = *(const f32x4*)&biasL[il * 64 + u * 16 + q * 4];
#pragma unroll
                for (int nt = 0; nt < 4; ++nt) hacc[uu][nt] = MFMA16(a1, b1own[nt], bi);
            }
            // mm1 pass 2: partner ld-chunk
            while (ACQ(&F[pn]) < g) {}
            h16x4 b1p[4];
#pragma unroll
            for (int nt = 0; nt < 4; ++nt)
                b1p[nt] = *(const h16x4*)&buf[pn * 1024 + (nt * 64 + lane) * 4];
#pragma unroll
            for (int uu = 0; uu < 2; ++uu) {
                const int u = 2 * sb + uu;
                const h16x4 a1 = *(const h16x4*)(A1L + (((il * 4 + u) * 2) + pn) * 256 + lane * 4);
#pragma unroll
                for (int nt = 0; nt < 4; ++nt) hacc[uu][nt] = MFMA16(a1, b1p[nt], hacc[uu][nt]);
            }
            if (sb == 1 && lane == 0) REL(&F[5], g);  // y0 consumed (loads complete before MFMA issue)
            // gelu -> own B2-x16 frags (regs)
            h16x4 b2own[2][4];
#pragma unroll
            for (int uu = 0; uu < 2; ++uu)
#pragma unroll
                for (int nt = 0; nt < 4; ++nt) {
                    half2 e0 = gelu_pk(pkrtz(hacc[uu][nt][0], hacc[uu][nt][1]));
                    half2 e1 = gelu_pk(pkrtz(hacc[uu][nt][2], hacc[uu][nt][3]));
                    b2own[uu][nt] = h4(e0, e1);
                }
            // h exchange + mm2 (two rounds through the 4KB buf)
            if (sb == 0) {
                while (ACQ(&F[5]) < g) {}   // partner done reading region0-y
#pragma unroll
                for (int uu = 0; uu < 2; ++uu)
#pragma unroll
                    for (int nt = 0; nt < 4; ++nt)
                        st4h(&buf[((uu * 4 + nt) * 64 + lane) * 4], lo2(b2own[uu][nt]), hi2(b2own[uu][nt]));
                if (lane == 0) REL(&F[2], g);
#pragma unroll
                for (int kc = 0; kc < 2; ++kc) {
                    const h16x4 a2 = *(const h16x4*)(A2L + ((il * 2 + sb) * 4 + kc) * 256 + lane * 4);
#pragma unroll
                    for (int nt = 0; nt < 4; ++nt) tok[nt] = MFMA16(a2, b2own[kc][nt], tok[nt]);
                }
                while (ACQ(&F[3]) < g) {}
#pragma unroll
                for (int kc = 2; kc < 4; ++kc) {
                    const h16x4 a2 = *(const h16x4*)(A2L + ((il * 2 + sb) * 4 + kc) * 256 + lane * 4);
#pragma unroll
                    for (int nt = 0; nt < 4; ++nt) {
                        const h16x4 b2p = *(const h16x4*)&buf[(((kc - 2) * 4 + nt) * 64 + lane) * 4];
                        tok[nt] = MFMA16(a2, b2p, tok[nt]);
                    }
                }
                if (lane == 0) REL(&F[4], g);   // h1 consumed
            } else {
#pragma unroll
                for (int kcl = 0; kcl < 2; ++kcl) {
                    const int kc = 2 + kcl;
                    const h16x4 a2 = *(const h16x4*)(A2L + ((il * 2 + sb) * 4 + kc) * 256 + lane * 4);
#pragma unroll
                    for (int nt = 0; nt < 4; ++nt) tok[nt] = MFMA16(a2, b2own[kcl][nt], tok[nt]);
                }
                while (ACQ(&F[2]) < g) {}
#pragma unroll
                for (int kc = 0; kc < 2; ++kc) {
                    const h16x4 a2 = *(const h16x4*)(A2L + ((il * 2 + sb) * 4 + kc) * 256 + lane * 4);
#pragma unroll
                    for (int nt = 0; nt < 4; ++nt) {
                        const h16x4 b2p = *(const h16x4*)&buf[((kc * 4 + nt) * 64 + lane) * 4];
                        tok[nt] = MFMA16(a2, b2p, tok[nt]);
                    }
                }
#pragma unroll
                for (int uu = 0; uu < 2; ++uu)
#pragma unroll
                    for (int nt = 0; nt < 4; ++nt)
                        st4h(&buf[((uu * 4 + nt) * 64 + lane) * 4], lo2(b2own[uu][nt]), hi2(b2own[uu][nt]));
                if (lane == 0) REL(&F[3], g);
            }

            // ======== channel mixing (wave-local) ========
            stats(mean, rsig);
            if (sb == 1) { while (ACQ(&F[4]) < g) {} }  // w0 done reading h1 (my scratch region)
            // LN2 -> B3 transpose scatter into own scratch
#pragma unroll
            for (int nt = 0; nt < 4; ++nt) {
                const float cng = biasL[1056 + il * 64 + nt * 16 + c];
                const float cnb = biasL[1248 + il * 64 + nt * 16 + c];
#pragma unroll
                for (int r = 0; r < 4; ++r) {
                    float v = fmaf((tok[nt][r] - mean[r]) * rsig[r], cng, cnb);
                    mysc[((nt >> 1) * 64 + (2 * (nt & 1) + (c >> 3)) * 16 + 4 * q + r) * 8 + (c & 7)] = f2h(v);
                }
            }
            h16x8 b3[2];
#pragma unroll
            for (int kc = 0; kc < 2; ++kc) b3[kc] = *(const h16x8*)&mysc[(kc * 64 + lane) * 8];
#pragma unroll
            for (int nt = 0; nt < 4; ++nt) tok[nt] += f4s(biasL[1440 + il * 64 + nt * 16 + c]);
            // mm3 (gelu -> A4 scatter) + mm4, by ch-half hh
#pragma unroll
            for (int hh = 0; hh < 2; ++hh) {
#pragma unroll
                for (int mm = 0; mm < 4; ++mm) {
                    const int mtc = hh * 4 + mm;
                    const h16x8 a30 = *(const h16x8*)(A3L + il * 8192 + (mtc * 2 + 0) * 512 + lane * 8);
                    const h16x8 a31 = *(const h16x8*)(A3L + il * 8192 + (mtc * 2 + 1) * 512 + lane * 8);
                    const f32x4 bi3 = *(const f32x4*)&biasL[288 + il * 128 + mtc * 16 + q * 4];
                    f32x4 acc = MFMA32(a30, b3[0], bi3);
                    acc = MFMA32(a31, b3[1], acc);
                    st4h(&mysc[(((mtc >> 1) & 1) * 64 + ((mtc & 1) * 2 + (q >> 1)) * 16 + c) * 8 + (q & 1) * 4],
                         gelu_pk(pkrtz(acc[0], acc[1])), gelu_pk(pkrtz(acc[2], acc[3])));
                }
                h16x8 a4[2];
#pragma unroll
                for (int kf = 0; kf < 2; ++kf) a4[kf] = *(const h16x8*)&mysc[(kf * 64 + lane) * 8];
#pragma unroll
                for (int nt = 0; nt < 4; ++nt) {
                    const h16x8 b40 = *(const h16x8*)(B4L + il * 8192 + (nt * 4 + hh * 2 + 0) * 512 + lane * 8);
                    const h16x8 b41 = *(const h16x8*)(B4L + il * 8192 + (nt * 4 + hh * 2 + 1) * 512 + lane * 8);
                    tok[nt] = MFMA32(a4[0], b40, tok[nt]);
                    tok[nt] = MFMA32(a4[1], b41, tok[nt]);
                }
            }
        }  // il

        // ======== head (wave-local) ========
        {
            f32x4 mean, rsig;
            stats(mean, rsig);
            f32x4 l4 = (tok[0] - mean) * f4s(gh_r[0]);
            l4 = __builtin_elementwise_fma(tok[1] - mean, f4s(gh_r[1]), l4);
            l4 = __builtin_elementwise_fma(tok[2] - mean, f4s(gh_r[2]), l4);
            l4 = __builtin_elementwise_fma(tok[3] - mean, f4s(gh_r[3]), l4);
            f32x4 ls;
#pragma unroll
            for (int r = 0; r < 4; ++r) ls[r] = rowsum16(l4[r]);
            f32x4 nv = cur + __builtin_elementwise_fma(rsig, ls, f4s(bh));
            nv = __builtin_elementwise_min(__builtin_elementwise_max(nv, f4s(0.f)), f4s(1.f));
            cur = nv;
            if (c == 0)
                *(f32x4*)(out + ((size_t)b * Tt + t) * 32 + sb * 16 + q * 4) = cur;
        }
    }  // t
}
}  // namespace

extern "C" void kernel_launch(void* const* d_in, const int* in_sizes, int n_in,
                              void* d_out, int out_size, void* d_ws, size_t ws_size,
                              hipStream_t stream) {
    (void)in_sizes; (void)n_in; (void)ws_size; (void)out_size;
    const float* phys    = (const float*)d_in[0];
    const float* latents = (const float*)d_in[1];
    const float* pos_emb = (const float*)d_in[2];
    const float* tokW    = (const float*)d_in[3];
    const float* tokb    = (const float*)d_in[4];
    const float* physW1  = (const float*)d_in[5];
    const float* physb1  = (const float*)d_in[6];
    const float* physW2  = (const float*)d_in[7];
    const float* physb2  = (const float*)d_in[8];
    const float* tn_g    = (const float*)d_in[9];
    const float* tn_b    = (const float*)d_in[10];
    const float* tiW     = (const float*)d_in[11];
    const float* tib     = (const float*)d_in[12];
    const float* toW     = (const float*)d_in[13];
    const float* tob     = (const float*)d_in[14];
    const float* cn_g    = (const float*)d_in[15];
    const float* cn_b    = (const float*)d_in[16];
    const float* ciW     = (const float*)d_in[17];
    const float* cib     = (const float*)d_in[18];
    const float* coW     = (const float*)d_in[19];
    const float* cob     = (const float*)d_in[20];
    const float* hn_g    = (const float*)d_in[21];
    const float* hn_b    = (const float*)d_in[22];
    const float* headW   = (const float*)d_in[23];
    const float* headb   = (const float*)d_in[24];

    lno_prep<<<dim3(256), dim3(256), 0, stream>>>(tiW, toW, ciW, coW, physW2, (short*)d_ws);
    lno_phys<<<dim3(131072), dim3(256), 0, stream>>>(phys, physW1, physb1, physW2, physb2,
                                                     (short*)d_out);
    // scan: 256 blocks (1/CU), 16 waves/block = 8 teams x 2 half-batch waves
    lno_scan<<<dim3(256), dim3(1024), 0, stream>>>(
        latents, pos_emb, tokW, tokb, tn_g, tn_b, tib, tob,
        cn_g, cn_b, cib, cob, hn_g, hn_b, headW, headb,
        (const short*)d_ws, (const short*)d_out, (float*)d_out);
}

// Round 9
// 6648.695 us; speedup vs baseline: 1.2072x; 1.0899x over previous
//
#include <hip/hip_runtime.h>
#include <math.h>

// Round 11b: LDS-fit fix of round 11 (comb table overflowed LDS by 6.6KB:
// 170624 > 163840). comb -> f16 registers peh[4] (8 VGPRs, ~1e-5 abs err).
// LDS now 162432 B. Everything else = r11.
//  - r10b measured: structure works (occ 40%, VALU 67%) but VGPR_Count=64
//    forced 3.8GB spill traffic. launch_bounds law: cap = 256/min_waves.
//    (1024,2) -> 128 cap; flat-workgroup 1024 also hard-caps at 128 (16
//    waves must co-reside at 4/SIMD; 512-reg pool/SIMD).
//  - half-batch teams, flag-based pairwise sync, no block barriers in loop.
//
// Fragment layouts (gfx950, verified r2-r10):
//   x32: A[m=lane&15][k=8q+j], B[k=8q+j][n=lane&15]
//   x16: A[m=lane&15][k=4q+j], B[k=4q+j][n=lane&15]
//   C (both): col=lane&15, row=4q+reg.

namespace {
constexpr int Tt = 256, NL = 3;

typedef float    f32x4 __attribute__((ext_vector_type(4)));
typedef _Float16 half2 __attribute__((ext_vector_type(2)));
typedef _Float16 h16x4 __attribute__((ext_vector_type(4)));
typedef _Float16 h16x8 __attribute__((ext_vector_type(8)));

#define MFMA32(a, b, c) __builtin_amdgcn_mfma_f32_16x16x32_f16((a), (b), (c), 0, 0, 0)
#define MFMA16(a, b, c) __builtin_amdgcn_mfma_f32_16x16x16f16((a), (b), (c), 0, 0, 0)
#define REL(p, v) __hip_atomic_store((p), (v), __ATOMIC_RELEASE, __HIP_MEMORY_SCOPE_WORKGROUP)
#define ACQ(p) __hip_atomic_load((p), __ATOMIC_ACQUIRE, __HIP_MEMORY_SCOPE_WORKGROUP)

__device__ __forceinline__ half2 h2c(float v) { return (half2)((_Float16)v); }
__device__ __forceinline__ f32x4 f4s(float v) { return (f32x4)v; }
__device__ __forceinline__ half2 pkrtz(float a, float b) {
    return __builtin_bit_cast(half2, __builtin_amdgcn_cvt_pkrtz(a, b));
}
__device__ __forceinline__ void st4h(short* p, half2 a, half2 b) {
    uint2 v;
    v.x = __builtin_bit_cast(unsigned int, a);
    v.y = __builtin_bit_cast(unsigned int, b);
    *(uint2*)p = v;
}
__device__ __forceinline__ h16x4 h4(half2 a, half2 b) {
    h16x4 v; v[0] = a[0]; v[1] = a[1]; v[2] = b[0]; v[3] = b[1]; return v;
}
__device__ __forceinline__ half2 lo2(h16x4 v) { half2 r; r[0] = v[0]; r[1] = v[1]; return r; }
__device__ __forceinline__ half2 hi2(h16x4 v) { half2 r; r[0] = v[2]; r[1] = v[3]; return r; }
// packed f16 GELU, no transcendentals (unchanged numerics from r5-r10)
__device__ __forceinline__ half2 gelu_pk(half2 x) {
    half2 tc = __builtin_elementwise_min(__builtin_elementwise_max(x, h2c(-3.0f)), h2c(3.0f));
    half2 s = (tc * tc) * h2c(0.125f);
    half2 p = s * h2c(0.1455169f) + h2c(-0.446340f);
    p = s * p + h2c(0.604927f);
    p = s * p + h2c(-0.529702f);
    p = s * p + h2c(0.3989423f);
    return x * (h2c(0.5f) + tc * p);
}
__device__ __forceinline__ float gelu_f(float x) {
    float tc = fminf(fmaxf(x, -3.f), 3.f);
    float s = tc * tc;
    float p = fmaf(s, 3.55266e-5f, -8.71758e-4f);
    p = fmaf(s, p, 9.45198e-3f);
    p = fmaf(s, p, -6.62128e-2f);
    p = fmaf(s, p, 0.3989423f);
    return x * fmaf(tc, p, 0.5f);
}
// sum across the 16-lane DPP row (all lanes get the total)
__device__ __forceinline__ float rowsum16(float x) {
    x += __builtin_bit_cast(float, __builtin_amdgcn_update_dpp(0, __builtin_bit_cast(int, x), 0x121, 0xf, 0xf, false));
    x += __builtin_bit_cast(float, __builtin_amdgcn_update_dpp(0, __builtin_bit_cast(int, x), 0x122, 0xf, 0xf, false));
    x += __builtin_bit_cast(float, __builtin_amdgcn_update_dpp(0, __builtin_bit_cast(int, x), 0x124, 0xf, 0xf, false));
    x += __builtin_bit_cast(float, __builtin_amdgcn_update_dpp(0, __builtin_bit_cast(int, x), 0x128, 0xf, 0xf, false));
    return x;
}
__device__ __forceinline__ short f2h(float x) {
    return __builtin_bit_cast(short, (_Float16)x);
}

// ws layout (shorts/f16):
//   A1 x16 frags [0,6144): tiles ((il*4+u)*2+kc)*256, elem lane*4+j
//       = tiW[il][ld=16kc+4q+j][th=16u+c]
//   A2 x16 frags [6144,12288): tiles ((il*2+sb)*4+kc)*256
//       = toW[il][th=16kc+4q+j][ld=16sb+c]
//   A3 x32 frags [12288,36864): ciW (as r5-r9)
//   B4 x32 frags [36864,61440): coW (as r5-r9)
//   W2F fp32 tail kept for layout (unused by scan)
__global__ void lno_prep(const float* __restrict__ tiW, const float* __restrict__ toW,
                         const float* __restrict__ ciW, const float* __restrict__ coW,
                         const float* __restrict__ physW2, short* __restrict__ wsf) {
    int id = blockIdx.x * 256 + threadIdx.x;  // 0..65535
    if (id < 6144) {            // A1 x16: m=th, k=ld-chunk
        int e = id & 255, tile = id >> 8;           // 24 tiles
        int lane = e >> 2, j = e & 3;
        int q = lane >> 4, cc = lane & 15;
        int kc = tile & 1, u = (tile >> 1) & 3, il = tile >> 3;
        wsf[id] = f2h(tiW[il * 2048 + (16 * kc + 4 * q + j) * 64 + 16 * u + cc]);
    } else if (id < 12288) {    // A2 x16: m=ld-half, k=th-chunk
        int t = id - 6144;
        int e = t & 255, tile = t >> 8;             // 24 tiles
        int lane = e >> 2, j = e & 3;
        int q = lane >> 4, cc = lane & 15;
        int kc = tile & 3, sb = (tile >> 2) & 1, il = tile >> 3;
        wsf[id] = f2h(toW[il * 2048 + (16 * kc + 4 * q + j) * 32 + 16 * sb + cc]);
    } else if (id < 36864) {    // A3 x32: m=ch, k=w
        int t = id - 12288;
        int j = t & 7, lane = (t >> 3) & 63, g = t >> 9;
        int il = g >> 4, mtc = (g >> 1) & 7, ks = g & 1;
        int m = mtc * 16 + (lane & 15), k = ks * 32 + (lane >> 4) * 8 + j;
        wsf[id] = f2h(ciW[il * 8192 + k * 128 + m]);
    } else if (id < 61440) {    // B4 x32: k=ch, n=w
        int t = id - 36864;
        int j = t & 7, lane = (t >> 3) & 63, g = t >> 9;
        int il = g >> 4, nt = (g >> 2) & 3, ks = g & 3;
        int n = nt * 16 + (lane & 15), k = ks * 32 + (lane >> 4) * 8 + j;
        wsf[id] = f2h(coW[il * 8192 + k * 64 + n]);
    } else if (id < 65536) {
        int t = id - 61440;
        int w = t >> 6, k = t & 63;
        ((float*)(wsf + 61440))[t] = physW2[k * 64 + w];
    }
}

// phys MLP pre-pass (unchanged): p stored f16 in d_out's [b,t] 128B slot,
// permuted so scan lane (q,c) reads its 4 values {w=nt*16+c} as one 8B load.
__global__ void lno_phys(const float* __restrict__ phys, const float* __restrict__ physW1,
                         const float* __restrict__ physb1, const float* __restrict__ physW2,
                         const float* __restrict__ physb2, short* __restrict__ pout) {
    __shared__ float hsh[4][64];
    const int lane = threadIdx.x & 63, wv = threadIdx.x >> 6;
    const size_t bt = (size_t)blockIdx.x * 4 + wv;
    const float* pt = phys + bt * 8;
    float4 px0 = *(const float4*)pt, px1 = *(const float4*)(pt + 4);
    float a = physb1[lane];
    a = fmaf(px0.x, physW1[0 * 64 + lane], a);
    a = fmaf(px0.y, physW1[1 * 64 + lane], a);
    a = fmaf(px0.z, physW1[2 * 64 + lane], a);
    a = fmaf(px0.w, physW1[3 * 64 + lane], a);
    a = fmaf(px1.x, physW1[4 * 64 + lane], a);
    a = fmaf(px1.y, physW1[5 * 64 + lane], a);
    a = fmaf(px1.z, physW1[6 * 64 + lane], a);
    a = fmaf(px1.w, physW1[7 * 64 + lane], a);
    hsh[wv][lane] = gelu_f(a);
    float acc = physb2[lane];
#pragma unroll
    for (int k = 0; k < 64; ++k) acc = fmaf(hsh[wv][k], physW2[k * 64 + lane], acc);
    pout[bt * 64 + (lane & 15) * 4 + (lane >> 4)] = f2h(acc);
}

// 1024 thr = 16 waves = 8 teams x 2 waves; 1 block/CU; 4 waves/SIMD.
// Flag protocol per layer (g = t*3+il+1): F[0/1]=y-ready(sb), F[5]=y0-consumed,
// F[2/3]=h0/h1-ready, F[4]=h1-consumed. pbuf/out alias d_out (read-before-
// write per wave as in r7-r10). LDS: 122880+32768+6528+256 = 162432 B.
__global__ __launch_bounds__(1024, 2) void lno_scan(
    const float* __restrict__ latents, const float* __restrict__ pos_emb,
    const float* __restrict__ tokW,    const float* __restrict__ tokb,
    const float* __restrict__ tn_g,    const float* __restrict__ tn_b,
    const float* __restrict__ tib,     const float* __restrict__ tob,
    const float* __restrict__ cn_g,    const float* __restrict__ cn_b,
    const float* __restrict__ cib,     const float* __restrict__ cob,
    const float* __restrict__ hn_g,    const float* __restrict__ hn_b,
    const float* __restrict__ headW,   const float* __restrict__ headb,
    const short* __restrict__ wsf,     const short* pbuf, float* out)
{
    __shared__ __align__(16) short wAll[61440];   // A1|A2|A3|B4
    __shared__ __align__(16) short tbuf[8][2048]; // 4KB per team
    __shared__ __align__(16) float biasL[1632];   // tib[0) tob[192) cib[288) tn_g[672)
                                                  // tn_b[864) cn_g[1056) cn_b[1248) cob[1440)
    __shared__ int flags[8][8];

    const int tid = threadIdx.x, lane = tid & 63, wv = tid >> 6;
    const int sb = wv & 1, tm = wv >> 1, pn = sb ^ 1;
    const int q = lane >> 4, c = lane & 15;
    const int b = blockIdx.x * 8 + tm;
    short* buf = tbuf[tm];
    short* mysc = buf + sb * 1024;   // wave-local channel scratch (== own y region)
    int* F = flags[tm];

    const short* A1L = wAll;
    const short* A2L = wAll + 6144;
    const short* A3L = wAll + 12288;
    const short* B4L = wAll + 36864;

    // ---- one-shot weight stage: 120 chunks of 1KB; waves 0..14 do 8 each ----
    if (wv < 15) {
        const unsigned int* src = (const unsigned int*)wsf;
#pragma unroll
        for (int i = 0; i < 8; ++i) {
            const int cid = wv * 8 + i;
            __builtin_amdgcn_global_load_lds(src + cid * 256 + lane * 4,
                                             (unsigned int*)&wAll[cid * 512], 16, 0, 0);
        }
    }
    // ---- one-shot bias/LN-param stage ----
    for (int i = tid; i < 192; i += 1024) {
        biasL[i] = tib[i];
        biasL[672 + i]  = tn_g[i];
        biasL[864 + i]  = tn_b[i];
        biasL[1056 + i] = cn_g[i];
        biasL[1248 + i] = cn_b[i];
        biasL[1440 + i] = cob[i];
    }
    for (int i = tid; i < 96;  i += 1024) biasL[192 + i] = tob[i];
    for (int i = tid; i < 384; i += 1024) biasL[288 + i] = cib[i];
    if (tid < 64) ((int*)flags)[tid] = 0;

    // ---- hoisted per-lane constants ----
    float tokw_r[4], gh_r[4];
#pragma unroll
    for (int nt = 0; nt < 4; ++nt) {
        tokw_r[nt] = tokW[nt * 16 + c];
        gh_r[nt]   = hn_g[nt * 16 + c] * headW[nt * 16 + c];
    }
    float bhp = 0.f;
#pragma unroll
    for (int nt = 0; nt < 4; ++nt) bhp = fmaf(hn_b[nt * 16 + c], headW[nt * 16 + c], bhp);
    const float bh = rowsum16(bhp) + headb[0];

    // pos_emb+tokb pre-sum, f16-packed: peh[r][nt] (8 VGPRs; values ~0.02)
    h16x4 peh[4];
#pragma unroll
    for (int r = 0; r < 4; ++r) {
        float v0 = pos_emb[(sb * 16 + q * 4 + r) * 64 +  0 + c] + tokb[ 0 + c];
        float v1 = pos_emb[(sb * 16 + q * 4 + r) * 64 + 16 + c] + tokb[16 + c];
        float v2 = pos_emb[(sb * 16 + q * 4 + r) * 64 + 32 + c] + tokb[32 + c];
        float v3 = pos_emb[(sb * 16 + q * 4 + r) * 64 + 48 + c] + tokb[48 + c];
        peh[r] = h4(pkrtz(v0, v1), pkrtz(v2, v3));
    }

    f32x4 cur = *(const f32x4*)(latents + b * 32 + sb * 16 + q * 4);
    f32x4 tok[4];

    __syncthreads();  // weights (vmcnt drained) + biasL/flags ready; only barrier.

    auto stats = [&](f32x4& mean, f32x4& rsig) {
        f32x4 s4 = (tok[0] + tok[1]) + (tok[2] + tok[3]);
        f32x4 q4 = tok[0] * tok[0];
        q4 = __builtin_elementwise_fma(tok[1], tok[1], q4);
        q4 = __builtin_elementwise_fma(tok[2], tok[2], q4);
        q4 = __builtin_elementwise_fma(tok[3], tok[3], q4);
#pragma unroll
        for (int r = 0; r < 4; ++r) {
            float ss = rowsum16(s4[r]);
            float qq = rowsum16(q4[r]);
            float m = ss * 0.015625f;
            float v = fmaf(-m, m, qq * 0.015625f);
            mean[r] = m;
            rsig[r] = __builtin_amdgcn_rsqf(v + 1e-5f);
        }
    };

    const short* pb = pbuf + (size_t)b * Tt * 64 + c * 4;
    h16x4 pvc = *(const h16x4*)pb;

#pragma unroll 1
    for (int t = 0; t < Tt; ++t) {
        const h16x4 pv = pvc;
        if (t + 1 < Tt) pvc = *(const h16x4*)(pb + (t + 1) * 64);

        // ======== token init (own rows) from f16 peh + pv ========
        {
            f32x4 pvx;
#pragma unroll
            for (int nt = 0; nt < 4; ++nt) pvx[nt] = (float)pv[nt];
#pragma unroll
            for (int r = 0; r < 4; ++r) {
#pragma unroll
                for (int nt = 0; nt < 4; ++nt)
                    tok[nt][r] = fmaf(cur[r], tokw_r[nt], (float)peh[r][nt] + pvx[nt]);
            }
        }

#pragma unroll 1
        for (int il = 0; il < NL; ++il) {
            const int g = t * 3 + il + 1;
            // ======== token mixing ========
            f32x4 mean, rsig;
            stats(mean, rsig);
            // LN1 -> own B1-x16 frags (regs) + write to own y region
            h16x4 b1own[4];
#pragma unroll
            for (int nt = 0; nt < 4; ++nt) {
                const float tng = biasL[672 + il * 64 + nt * 16 + c];
                const float tnb = biasL[864 + il * 64 + nt * 16 + c];
                f32x4 y = __builtin_elementwise_fma((tok[nt] - mean) * rsig,
                                                    f4s(tng), f4s(tnb));
                half2 d0 = pkrtz(y[0], y[1]), d1 = pkrtz(y[2], y[3]);
                b1own[nt] = h4(d0, d1);
                st4h(&buf[sb * 1024 + (nt * 64 + lane) * 4], d0, d1);
            }
            if (lane == 0) REL(&F[sb], g);
            // tob pre-add (own rows)
            {
                const f32x4 tb = *(const f32x4*)&biasL[192 + il * 32 + sb * 16 + q * 4];
#pragma unroll
                for (int nt = 0; nt < 4; ++nt) tok[nt] += tb;
            }
            // wait partner y, load its frags once
            while (ACQ(&F[pn]) < g) {}
            h16x4 b1p[4];
#pragma unroll
            for (int nt = 0; nt < 4; ++nt)
                b1p[nt] = *(const h16x4*)&buf[pn * 1024 + (nt * 64 + lane) * 4];
            if (sb == 1 && lane == 0) REL(&F[5], g);  // y0 consumed (REL orders after reads)
            // mm1: per u, both K-chunks chained -> gelu -> B2-x16 frags (regs)
            h16x4 b2own[2][4];
#pragma unroll
            for (int uu = 0; uu < 2; ++uu) {
                const int u = 2 * sb + uu;
                const h16x4 a1o = *(const h16x4*)(A1L + (((il * 4 + u) * 2) + sb) * 256 + lane * 4);
                const h16x4 a1p = *(const h16x4*)(A1L + (((il * 4 + u) * 2) + pn) * 256 + lane * 4);
                const f32x4 bi = *(const f32x4*)&biasL[il * 64 + u * 16 + q * 4];
#pragma unroll
                for (int nt = 0; nt < 4; ++nt) {
                    f32x4 hv = MFMA16(a1o, b1own[nt], bi);
                    hv = MFMA16(a1p, b1p[nt], hv);
                    half2 e0 = gelu_pk(pkrtz(hv[0], hv[1]));
                    half2 e1 = gelu_pk(pkrtz(hv[2], hv[3]));
                    b2own[uu][nt] = h4(e0, e1);
                }
            }
            // h exchange + mm2 (two rounds through the 4KB buf)
            if (sb == 0) {
                while (ACQ(&F[5]) < g) {}   // partner done reading region0-y
#pragma unroll
                for (int uu = 0; uu < 2; ++uu)
#pragma unroll
                    for (int nt = 0; nt < 4; ++nt)
                        st4h(&buf[((uu * 4 + nt) * 64 + lane) * 4], lo2(b2own[uu][nt]), hi2(b2own[uu][nt]));
                if (lane == 0) REL(&F[2], g);
#pragma unroll
                for (int kc = 0; kc < 2; ++kc) {
                    const h16x4 a2 = *(const h16x4*)(A2L + ((il * 2 + sb) * 4 + kc) * 256 + lane * 4);
#pragma unroll
                    for (int nt = 0; nt < 4; ++nt) tok[nt] = MFMA16(a2, b2own[kc][nt], tok[nt]);
                }
                while (ACQ(&F[3]) < g) {}
#pragma unroll
                for (int kc = 2; kc < 4; ++kc) {
                    const h16x4 a2 = *(const h16x4*)(A2L + ((il * 2 + sb) * 4 + kc) * 256 + lane * 4);
#pragma unroll
                    for (int nt = 0; nt < 4; ++nt) {
                        const h16x4 b2p = *(const h16x4*)&buf[(((kc - 2) * 4 + nt) * 64 + lane) * 4];
                        tok[nt] = MFMA16(a2, b2p, tok[nt]);
                    }
                }
                if (lane == 0) REL(&F[4], g);   // h1 consumed
            } else {
#pragma unroll
                for (int kcl = 0; kcl < 2; ++kcl) {
                    const int kc = 2 + kcl;
                    const h16x4 a2 = *(const h16x4*)(A2L + ((il * 2 + sb) * 4 + kc) * 256 + lane * 4);
#pragma unroll
                    for (int nt = 0; nt < 4; ++nt) tok[nt] = MFMA16(a2, b2own[kcl][nt], tok[nt]);
                }
                while (ACQ(&F[2]) < g) {}
#pragma unroll
                for (int kc = 0; kc < 2; ++kc) {
                    const h16x4 a2 = *(const h16x4*)(A2L + ((il * 2 + sb) * 4 + kc) * 256 + lane * 4);
#pragma unroll
                    for (int nt = 0; nt < 4; ++nt) {
                        const h16x4 b2p = *(const h16x4*)&buf[((kc * 4 + nt) * 64 + lane) * 4];
                        tok[nt] = MFMA16(a2, b2p, tok[nt]);
                    }
                }
#pragma unroll
                for (int uu = 0; uu < 2; ++uu)
#pragma unroll
                    for (int nt = 0; nt < 4; ++nt)
                        st4h(&buf[((uu * 4 + nt) * 64 + lane) * 4], lo2(b2own[uu][nt]), hi2(b2own[uu][nt]));
                if (lane == 0) REL(&F[3], g);
            }

            // ======== channel mixing (wave-local) ========
            stats(mean, rsig);
            if (sb == 1) { while (ACQ(&F[4]) < g) {} }  // w0 done reading h1 (my scratch region)
            // LN2 -> B3 transpose scatter into own scratch
#pragma unroll
            for (int nt = 0; nt < 4; ++nt) {
                const float cng = biasL[1056 + il * 64 + nt * 16 + c];
                const float cnb = biasL[1248 + il * 64 + nt * 16 + c];
#pragma unroll
                for (int r = 0; r < 4; ++r) {
                    float v = fmaf((tok[nt][r] - mean[r]) * rsig[r], cng, cnb);
                    mysc[((nt >> 1) * 64 + (2 * (nt & 1) + (c >> 3)) * 16 + 4 * q + r) * 8 + (c & 7)] = f2h(v);
                }
            }
            h16x8 b3[2];
#pragma unroll
            for (int kc = 0; kc < 2; ++kc) b3[kc] = *(const h16x8*)&mysc[(kc * 64 + lane) * 8];
#pragma unroll
            for (int nt = 0; nt < 4; ++nt) tok[nt] += f4s(biasL[1440 + il * 64 + nt * 16 + c]);
            // mm3 (gelu -> A4 scatter) + mm4, by ch-half hh
#pragma unroll
            for (int hh = 0; hh < 2; ++hh) {
#pragma unroll
                for (int mm = 0; mm < 4; ++mm) {
                    const int mtc = hh * 4 + mm;
                    const h16x8 a30 = *(const h16x8*)(A3L + il * 8192 + (mtc * 2 + 0) * 512 + lane * 8);
                    const h16x8 a31 = *(const h16x8*)(A3L + il * 8192 + (mtc * 2 + 1) * 512 + lane * 8);
                    const f32x4 bi3 = *(const f32x4*)&biasL[288 + il * 128 + mtc * 16 + q * 4];
                    f32x4 acc = MFMA32(a30, b3[0], bi3);
                    acc = MFMA32(a31, b3[1], acc);
                    st4h(&mysc[(((mtc >> 1) & 1) * 64 + ((mtc & 1) * 2 + (q >> 1)) * 16 + c) * 8 + (q & 1) * 4],
                         gelu_pk(pkrtz(acc[0], acc[1])), gelu_pk(pkrtz(acc[2], acc[3])));
                }
                h16x8 a4[2];
#pragma unroll
                for (int kf = 0; kf < 2; ++kf) a4[kf] = *(const h16x8*)&mysc[(kf * 64 + lane) * 8];
#pragma unroll
                for (int nt = 0; nt < 4; ++nt) {
                    const h16x8 b40 = *(const h16x8*)(B4L + il * 8192 + (nt * 4 + hh * 2 + 0) * 512 + lane * 8);
                    const h16x8 b41 = *(const h16x8*)(B4L + il * 8192 + (nt * 4 + hh * 2 + 1) * 512 + lane * 8);
                    tok[nt] = MFMA32(a4[0], b40, tok[nt]);
                    tok[nt] = MFMA32(a4[1], b41, tok[nt]);
                }
            }
        }  // il

        // ======== head (wave-local) ========
        {
            f32x4 mean, rsig;
            stats(mean, rsig);
            f32x4 l4 = (tok[0] - mean) * f4s(gh_r[0]);
            l4 = __builtin_elementwise_fma(tok[1] - mean, f4s(gh_r[1]), l4);
            l4 = __builtin_elementwise_fma(tok[2] - mean, f4s(gh_r[2]), l4);
            l4 = __builtin_elementwise_fma(tok[3] - mean, f4s(gh_r[3]), l4);
            f32x4 ls;
#pragma unroll
            for (int r = 0; r < 4; ++r) ls[r] = rowsum16(l4[r]);
            f32x4 nv = cur + __builtin_elementwise_fma(rsig, ls, f4s(bh));
            nv = __builtin_elementwise_min(__builtin_elementwise_max(nv, f4s(0.f)), f4s(1.f));
            cur = nv;
            if (c == 0)
                *(f32x4*)(out + ((size_t)b * Tt + t) * 32 + sb * 16 + q * 4) = cur;
        }
    }  // t
}
}  // namespace

extern "C" void kernel_launch(void* const* d_in, const int* in_sizes, int n_in,
                              void* d_out, int out_size, void* d_ws, size_t ws_size,
                              hipStream_t stream) {
    (void)in_sizes; (void)n_in; (void)ws_size; (void)out_size;
    const float* phys    = (const float*)d_in[0];
    const float* latents = (const float*)d_in[1];
    const float* pos_emb = (const float*)d_in[2];
    const float* tokW    = (const float*)d_in[3];
    const float* tokb    = (const float*)d_in[4];
    const float* physW1  = (const float*)d_in[5];
    const float* physb1  = (const float*)d_in[6];
    const float* physW2  = (const float*)d_in[7];
    const float* physb2  = (const float*)d_in[8];
    const float* tn_g    = (const float*)d_in[9];
    const float* tn_b    = (const float*)d_in[10];
    const float* tiW     = (const float*)d_in[11];
    const float* tib     = (const float*)d_in[12];
    const float* toW     = (const float*)d_in[13];
    const float* tob     = (const float*)d_in[14];
    const float* cn_g    = (const float*)d_in[15];
    const float* cn_b    = (const float*)d_in[16];
    const float* ciW     = (const float*)d_in[17];
    const float* cib     = (const float*)d_in[18];
    const float* coW     = (const float*)d_in[19];
    const float* cob     = (const float*)d_in[20];
    const float* hn_g    = (const float*)d_in[21];
    const float* hn_b    = (const float*)d_in[22];
    const float* headW   = (const float*)d_in[23];
    const float* headb   = (const float*)d_in[24];

    lno_prep<<<dim3(256), dim3(256), 0, stream>>>(tiW, toW, ciW, coW, physW2, (short*)d_ws);
    lno_phys<<<dim3(131072), dim3(256), 0, stream>>>(phys, physW1, physb1, physW2, physb2,
                                                     (short*)d_out);
    // scan: 256 blocks (1/CU), 16 waves/block = 8 teams x 2 half-batch waves
    lno_scan<<<dim3(256), dim3(1024), 0, stream>>>(
        latents, pos_emb, tokW, tokb, tn_g, tn_b, tib, tob,
        cn_g, cn_b, cib, cob, hn_g, hn_b, headW, headb,
        (const short*)d_ws, (const short*)d_out, (float*)d_out);
}

// Round 10
// 6058.598 us; speedup vs baseline: 1.3247x; 1.0974x over previous
//
#include <hip/hip_runtime.h>
#include <math.h>

// Round 12: r8 chassis + in-register token mixing (x16 MFMA identity).
//  - r9/r10/r11 measured: dual-stream ILP -22%, 4-wave/SIMD teams -7% even
//    spill-free. TLP/ILP exhausted; the per-wave phase chain is the cost.
//  - Key identity (verified in r10/r11, absmax unchanged): C-layout piece
//    C[row=4q+r][*] == x16 B-frag B[k=4q+j][*] (j==r). In a full-batch wave
//    both mm1's B (LN1 y, K=LD) and mm2's B (gelu h, K=TH) are own C-layout
//    regs -> token mixing needs ZERO LDS data round-trips (was ~36 ops + 3
//    lgkmcnt wait-phases per layer). mm1/mm2 = 64 x16 MFMA (same FLOPs).
//  - Channel mixing unchanged from r8 (its transposes are inherent).
//  - launch_bounds(512,1): LDS (162KB) already caps 1 block/CU = 8 waves;
//    uncapping VGPR (was 128) removes spill risk for +16-30 live regs.
//  - pe+tokb pre-sum packed f16 (peh, 16 VGPR vs 36) per r11b.
//
// Fragment layouts (gfx950, verified r2-r11):
//   x32: A[m=lane&15][k=8q+j], B[k=8q+j][n=lane&15]
//   x16: A[m=lane&15][k=4q+j], B[k=4q+j][n=lane&15]
//   C (both): col=lane&15, row=4q+reg.

namespace {
constexpr int Tt = 256, NL = 3;

typedef float    f32x4 __attribute__((ext_vector_type(4)));
typedef _Float16 half2 __attribute__((ext_vector_type(2)));
typedef _Float16 h16x4 __attribute__((ext_vector_type(4)));
typedef _Float16 h16x8 __attribute__((ext_vector_type(8)));

#define MFMA32(a, b, c) __builtin_amdgcn_mfma_f32_16x16x32_f16((a), (b), (c), 0, 0, 0)
#define MFMA16(a, b, c) __builtin_amdgcn_mfma_f32_16x16x16f16((a), (b), (c), 0, 0, 0)

__device__ __forceinline__ half2 h2c(float v) { return (half2)((_Float16)v); }
__device__ __forceinline__ f32x4 f4s(float v) { return (f32x4)v; }
__device__ __forceinline__ half2 pkrtz(float a, float b) {
    return __builtin_bit_cast(half2, __builtin_amdgcn_cvt_pkrtz(a, b));
}
__device__ __forceinline__ void st4h(short* p, half2 a, half2 b) {
    uint2 v;
    v.x = __builtin_bit_cast(unsigned int, a);
    v.y = __builtin_bit_cast(unsigned int, b);
    *(uint2*)p = v;
}
__device__ __forceinline__ h16x4 h4(half2 a, half2 b) {
    h16x4 v; v[0] = a[0]; v[1] = a[1]; v[2] = b[0]; v[3] = b[1]; return v;
}
// packed f16 GELU, no transcendentals (unchanged numerics from r5-r11)
__device__ __forceinline__ half2 gelu_pk(half2 x) {
    half2 tc = __builtin_elementwise_min(__builtin_elementwise_max(x, h2c(-3.0f)), h2c(3.0f));
    half2 s = (tc * tc) * h2c(0.125f);
    half2 p = s * h2c(0.1455169f) + h2c(-0.446340f);
    p = s * p + h2c(0.604927f);
    p = s * p + h2c(-0.529702f);
    p = s * p + h2c(0.3989423f);
    return x * (h2c(0.5f) + tc * p);
}
__device__ __forceinline__ float gelu_f(float x) {
    float tc = fminf(fmaxf(x, -3.f), 3.f);
    float s = tc * tc;
    float p = fmaf(s, 3.55266e-5f, -8.71758e-4f);
    p = fmaf(s, p, 9.45198e-3f);
    p = fmaf(s, p, -6.62128e-2f);
    p = fmaf(s, p, 0.3989423f);
    return x * fmaf(tc, p, 0.5f);
}
// sum across the 16-lane DPP row (all lanes get the total)
__device__ __forceinline__ float rowsum16(float x) {
    x += __builtin_bit_cast(float, __builtin_amdgcn_update_dpp(0, __builtin_bit_cast(int, x), 0x121, 0xf, 0xf, false));
    x += __builtin_bit_cast(float, __builtin_amdgcn_update_dpp(0, __builtin_bit_cast(int, x), 0x122, 0xf, 0xf, false));
    x += __builtin_bit_cast(float, __builtin_amdgcn_update_dpp(0, __builtin_bit_cast(int, x), 0x124, 0xf, 0xf, false));
    x += __builtin_bit_cast(float, __builtin_amdgcn_update_dpp(0, __builtin_bit_cast(int, x), 0x128, 0xf, 0xf, false));
    return x;
}
__device__ __forceinline__ short f2h(float x) {
    return __builtin_bit_cast(short, (_Float16)x);
}

// ws layout (shorts/f16) — identical to r11b's prep:
//   A1 x16 frags [0,6144): tiles ((il*4+u)*2+kc)*256, elem lane*4+j
//       = tiW[il][ld=16kc+4q+j][th=16u+c]
//   A2 x16 frags [6144,12288): tiles ((il*2+mt)*4+kc)*256
//       = toW[il][th=16kc+4q+j][ld=16mt+c]
//   A3 x32 frags [12288,36864): ciW (as r5-r9)
//   B4 x32 frags [36864,61440): coW (as r5-r9)
//   W2F fp32 tail kept for layout (unused by scan)
__global__ void lno_prep(const float* __restrict__ tiW, const float* __restrict__ toW,
                         const float* __restrict__ ciW, const float* __restrict__ coW,
                         const float* __restrict__ physW2, short* __restrict__ wsf) {
    int id = blockIdx.x * 256 + threadIdx.x;  // 0..65535
    if (id < 6144) {            // A1 x16: m=th, k=ld-chunk
        int e = id & 255, tile = id >> 8;           // 24 tiles
        int lane = e >> 2, j = e & 3;
        int q = lane >> 4, cc = lane & 15;
        int kc = tile & 1, u = (tile >> 1) & 3, il = tile >> 3;
        wsf[id] = f2h(tiW[il * 2048 + (16 * kc + 4 * q + j) * 64 + 16 * u + cc]);
    } else if (id < 12288) {    // A2 x16: m=ld-half, k=th-chunk
        int t = id - 6144;
        int e = t & 255, tile = t >> 8;             // 24 tiles
        int lane = e >> 2, j = e & 3;
        int q = lane >> 4, cc = lane & 15;
        int kc = tile & 3, mt = (tile >> 2) & 1, il = tile >> 3;
        wsf[id] = f2h(toW[il * 2048 + (16 * kc + 4 * q + j) * 32 + 16 * mt + cc]);
    } else if (id < 36864) {    // A3 x32: m=ch, k=w
        int t = id - 12288;
        int j = t & 7, lane = (t >> 3) & 63, g = t >> 9;
        int il = g >> 4, mtc = (g >> 1) & 7, ks = g & 1;
        int m = mtc * 16 + (lane & 15), k = ks * 32 + (lane >> 4) * 8 + j;
        wsf[id] = f2h(ciW[il * 8192 + k * 128 + m]);
    } else if (id < 61440) {    // B4 x32: k=ch, n=w
        int t = id - 36864;
        int j = t & 7, lane = (t >> 3) & 63, g = t >> 9;
        int il = g >> 4, nt = (g >> 2) & 3, ks = g & 3;
        int n = nt * 16 + (lane & 15), k = ks * 32 + (lane >> 4) * 8 + j;
        wsf[id] = f2h(coW[il * 8192 + k * 64 + n]);
    } else if (id < 65536) {
        int t = id - 61440;
        int w = t >> 6, k = t & 63;
        ((float*)(wsf + 61440))[t] = physW2[k * 64 + w];
    }
}

// phys MLP pre-pass (unchanged): p stored f16 in d_out's [b,t] 128B slot,
// permuted so scan lane (q,c) reads its 4 values {w=nt*16+c} as one 8B load.
__global__ void lno_phys(const float* __restrict__ phys, const float* __restrict__ physW1,
                         const float* __restrict__ physb1, const float* __restrict__ physW2,
                         const float* __restrict__ physb2, short* __restrict__ pout) {
    __shared__ float hsh[4][64];
    const int lane = threadIdx.x & 63, wv = threadIdx.x >> 6;
    const size_t bt = (size_t)blockIdx.x * 4 + wv;
    const float* pt = phys + bt * 8;
    float4 px0 = *(const float4*)pt, px1 = *(const float4*)(pt + 4);
    float a = physb1[lane];
    a = fmaf(px0.x, physW1[0 * 64 + lane], a);
    a = fmaf(px0.y, physW1[1 * 64 + lane], a);
    a = fmaf(px0.z, physW1[2 * 64 + lane], a);
    a = fmaf(px0.w, physW1[3 * 64 + lane], a);
    a = fmaf(px1.x, physW1[4 * 64 + lane], a);
    a = fmaf(px1.y, physW1[5 * 64 + lane], a);
    a = fmaf(px1.z, physW1[6 * 64 + lane], a);
    a = fmaf(px1.w, physW1[7 * 64 + lane], a);
    hsh[wv][lane] = gelu_f(a);
    float acc = physb2[lane];
#pragma unroll
    for (int k = 0; k < 64; ++k) acc = fmaf(hsh[wv][k], physW2[k * 64 + lane], acc);
    pout[bt * 64 + (lane & 15) * 4 + (lane >> 4)] = f2h(acc);
}

// block = 512 thr = 8 waves = 8 independent batches (r8 chassis). All weights
// in LDS (staged once); no barriers in the t loop. pbuf/out alias d_out
// (read-before-write per wave, as r7-r11).
__global__ __launch_bounds__(512, 1) void lno_scan(
    const float* __restrict__ latents, const float* __restrict__ pos_emb,
    const float* __restrict__ tokW,    const float* __restrict__ tokb,
    const float* __restrict__ tn_g,    const float* __restrict__ tn_b,
    const float* __restrict__ tib,     const float* __restrict__ tob,
    const float* __restrict__ cn_g,    const float* __restrict__ cn_b,
    const float* __restrict__ cib,     const float* __restrict__ cob,
    const float* __restrict__ hn_g,    const float* __restrict__ hn_b,
    const float* __restrict__ headW,   const float* __restrict__ headb,
    const short* __restrict__ wsf,     const short* pbuf, float* out)
{
    __shared__ __align__(16) short wAll[61440];   // A1|A2|A3|B4
    __shared__ __align__(16) short scr[8][2048];  // per-wave channel-mix scratch
    __shared__ __align__(16) float biasL[1632];   // tib[0) tob[192) cib[288) tn_g[672)
                                                  // tn_b[864) cn_g[1056) cn_b[1248) cob[1440)

    const int tid = threadIdx.x, lane = tid & 63, wv = tid >> 6;
    const int q = lane >> 4, c = lane & 15;
    const int b = blockIdx.x * 8 + wv;
    short* sc = scr[wv];

    const short* A1L = wAll;
    const short* A2L = wAll + 6144;
    const short* A3L = wAll + 12288;
    const short* B4L = wAll + 36864;

    // ---- one-shot weight stage: 120 chunks of 1KB, wave wv does 15 ----
    {
        const unsigned int* src = (const unsigned int*)wsf;
#pragma unroll
        for (int i = 0; i < 15; ++i) {
            const int cid = wv * 15 + i;
            __builtin_amdgcn_global_load_lds(src + cid * 256 + lane * 4,
                                             (unsigned int*)&wAll[cid * 512], 16, 0, 0);
        }
    }
    // ---- one-shot bias/LN-param stage ----
    for (int i = tid; i < 192; i += 512) {
        biasL[i] = tib[i];
        biasL[672 + i]  = tn_g[i];
        biasL[864 + i]  = tn_b[i];
        biasL[1056 + i] = cn_g[i];
        biasL[1248 + i] = cn_b[i];
        biasL[1440 + i] = cob[i];
    }
    for (int i = tid; i < 96;  i += 512) biasL[192 + i] = tob[i];
    for (int i = tid; i < 384; i += 512) biasL[288 + i] = cib[i];

    // ---- hoisted per-lane constants ----
    float tokw_r[4], gh_r[4];
#pragma unroll
    for (int nt = 0; nt < 4; ++nt) {
        tokw_r[nt] = tokW[nt * 16 + c];
        gh_r[nt]   = hn_g[nt * 16 + c] * headW[nt * 16 + c];
    }
    float bhp = 0.f;
#pragma unroll
    for (int nt = 0; nt < 4; ++nt) bhp = fmaf(hn_b[nt * 16 + c], headW[nt * 16 + c], bhp);
    const float bh = rowsum16(bhp) + headb[0];

    // pos_emb+tokb pre-sum, f16-packed: peh[mt][r][nt-packed] (16 VGPR)
    h16x4 peh[2][4];
#pragma unroll
    for (int mt = 0; mt < 2; ++mt)
#pragma unroll
        for (int r = 0; r < 4; ++r) {
            const int row = mt * 16 + q * 4 + r;
            float v0 = pos_emb[row * 64 +  0 + c] + tokb[ 0 + c];
            float v1 = pos_emb[row * 64 + 16 + c] + tokb[16 + c];
            float v2 = pos_emb[row * 64 + 32 + c] + tokb[32 + c];
            float v3 = pos_emb[row * 64 + 48 + c] + tokb[48 + c];
            peh[mt][r] = h4(pkrtz(v0, v1), pkrtz(v2, v3));
        }

    f32x4 cur8[2];
#pragma unroll
    for (int mt = 0; mt < 2; ++mt)
        cur8[mt] = *(const f32x4*)(latents + b * 32 + mt * 16 + q * 4);

    f32x4 tok[2][4];

    __syncthreads();  // weights (vmcnt drained) + biasL ready; last barrier.

    auto stats = [&](f32x4 (&mean)[2], f32x4 (&rsig)[2]) {
#pragma unroll
        for (int mt = 0; mt < 2; ++mt) {
            f32x4 s4 = (tok[mt][0] + tok[mt][1]) + (tok[mt][2] + tok[mt][3]);
            f32x4 q4 = tok[mt][0] * tok[mt][0];
            q4 = __builtin_elementwise_fma(tok[mt][1], tok[mt][1], q4);
            q4 = __builtin_elementwise_fma(tok[mt][2], tok[mt][2], q4);
            q4 = __builtin_elementwise_fma(tok[mt][3], tok[mt][3], q4);
#pragma unroll
            for (int r = 0; r < 4; ++r) {
                float ss = rowsum16(s4[r]);
                float qq = rowsum16(q4[r]);
                float m = ss * 0.015625f;
                float v = fmaf(-m, m, qq * 0.015625f);
                mean[mt][r] = m;
                rsig[mt][r] = __builtin_amdgcn_rsqf(v + 1e-5f);
            }
        }
    };

    const short* pb = pbuf + (size_t)b * Tt * 64 + c * 4;
    h16x4 pvc = *(const h16x4*)pb;

#pragma unroll 1
    for (int t = 0; t < Tt; ++t) {
        const h16x4 pv = pvc;
        if (t + 1 < Tt) pvc = *(const h16x4*)(pb + (t + 1) * 64);

        // ======== token init from f16 peh + pv ========
        {
            f32x4 pvx;
#pragma unroll
            for (int nt = 0; nt < 4; ++nt) pvx[nt] = (float)pv[nt];
#pragma unroll
            for (int mt = 0; mt < 2; ++mt)
#pragma unroll
                for (int r = 0; r < 4; ++r) {
#pragma unroll
                    for (int nt = 0; nt < 4; ++nt)
                        tok[nt == 0 ? mt : mt][nt][r] =  // keep writes grouped by nt below
                            0.f;
                }
            // (computed directly below to avoid the zero-init being kept)
#pragma unroll
            for (int mt = 0; mt < 2; ++mt)
#pragma unroll
                for (int r = 0; r < 4; ++r) {
#pragma unroll
                    for (int nt = 0; nt < 4; ++nt)
                        tok[mt][nt][r] = fmaf(cur8[mt][r], tokw_r[nt],
                                              (float)peh[mt][r][nt] + pvx[nt]);
                }
        }

#pragma unroll
        for (int il = 0; il < NL; ++il) {
            // ======== token mixing (in-register, x16 MFMA) ========
            f32x4 mean[2], rsig[2];
            stats(mean, rsig);
            // LN1 -> y x16 B-frags in regs (yh[mt][nt], j==r)
            h16x4 yh[2][4];
#pragma unroll
            for (int nt = 0; nt < 4; ++nt) {
                const float tng = biasL[672 + il * 64 + nt * 16 + c];
                const float tnb = biasL[864 + il * 64 + nt * 16 + c];
#pragma unroll
                for (int mt = 0; mt < 2; ++mt) {
                    f32x4 y = __builtin_elementwise_fma((tok[mt][nt] - mean[mt]) * rsig[mt],
                                                        f4s(tng), f4s(tnb));
                    yh[mt][nt] = h4(pkrtz(y[0], y[1]), pkrtz(y[2], y[3]));
                }
            }
            // tob pre-add (per-row); mm2 then accumulates in place
#pragma unroll
            for (int mt = 0; mt < 2; ++mt) {
                const f32x4 tb = *(const f32x4*)&biasL[192 + il * 32 + mt * 16 + q * 4];
#pragma unroll
                for (int nt = 0; nt < 4; ++nt) tok[mt][nt] += tb;
            }
            // mm1: h = gelu(tiW^T y + tib); output C-pieces ARE mm2's B-frags
            h16x4 b2[4][4];
#pragma unroll
            for (int u = 0; u < 4; ++u) {
                const h16x4 a1k0 = *(const h16x4*)(A1L + ((il * 4 + u) * 2 + 0) * 256 + lane * 4);
                const h16x4 a1k1 = *(const h16x4*)(A1L + ((il * 4 + u) * 2 + 1) * 256 + lane * 4);
                const f32x4 bi = *(const f32x4*)&biasL[il * 64 + u * 16 + q * 4];
#pragma unroll
                for (int nt = 0; nt < 4; ++nt) {
                    f32x4 hv = MFMA16(a1k0, yh[0][nt], bi);
                    hv = MFMA16(a1k1, yh[1][nt], hv);
                    b2[u][nt] = h4(gelu_pk(pkrtz(hv[0], hv[1])),
                                   gelu_pk(pkrtz(hv[2], hv[3])));
                }
            }
            // mm2: tok += toW^T h, all operands in regs/LDS-weights
#pragma unroll
            for (int mt = 0; mt < 2; ++mt)
#pragma unroll
                for (int kc = 0; kc < 4; ++kc) {
                    const h16x4 a2 = *(const h16x4*)(A2L + ((il * 2 + mt) * 4 + kc) * 256 + lane * 4);
#pragma unroll
                    for (int nt = 0; nt < 4; ++nt)
                        tok[mt][nt] = MFMA16(a2, b2[kc][nt], tok[mt][nt]);
                }

            // ======== channel mixing (r8-verbatim: transposes inherent) ========
            stats(mean, rsig);
            float cng[4], cnb[4];
#pragma unroll
            for (int nt = 0; nt < 4; ++nt) {
                cng[nt] = biasL[1056 + il * 64 + nt * 16 + c];
                cnb[nt] = biasL[1248 + il * 64 + nt * 16 + c];
            }
            // LN2 -> sc (B3 frags, swizzled slots), packed apply + scalar b16 scatter
#pragma unroll
            for (int mt = 0; mt < 2; ++mt)
#pragma unroll
                for (int nt = 0; nt < 4; ++nt) {
                    f32x4 v4 = __builtin_elementwise_fma((tok[mt][nt] - mean[mt]) * rsig[mt],
                                                         f4s(cng[nt]), f4s(cnb[nt]));
#pragma unroll
                    for (int r = 0; r < 4; ++r)
                        sc[(mt * 2 + (nt >> 1)) * 512 +
                           (q * 2 + (c >> 3) + 16 * r + 8 * (nt & 1)) * 8 + (c & 7)] = f2h(v4[r]);
                }
            h16x8 b3[4];
            {
                const int lp = ((c >> 2) * 2 + (q & 1)) + 8 * ((c & 3) * 2 + (q >> 1));
#pragma unroll
                for (int F = 0; F < 4; ++F) b3[F] = *(const h16x8*)&sc[F * 512 + lp * 8];
            }
            // pre-add cob (per-col); mm4 accumulates in place
#pragma unroll
            for (int nt = 0; nt < 4; ++nt) {
                const f32x4 cv = f4s(biasL[1440 + il * 64 + nt * 16 + c]);
#pragma unroll
                for (int mt = 0; mt < 2; ++mt) tok[mt][nt] += cv;
            }
            // mm3 (gelu -> sc) + mm4, by ch-half hh
#pragma unroll
            for (int hh = 0; hh < 2; ++hh) {
#pragma unroll
                for (int mm = 0; mm < 4; ++mm) {
                    const int mtc = hh * 4 + mm;
                    const h16x8 a30 = *(const h16x8*)(A3L + il * 8192 + (mtc * 2 + 0) * 512 + lane * 8);
                    const h16x8 a31 = *(const h16x8*)(A3L + il * 8192 + (mtc * 2 + 1) * 512 + lane * 8);
                    const f32x4 bi3 = *(const f32x4*)&biasL[288 + il * 128 + mtc * 16 + q * 4];
#pragma unroll
                    for (int ntl = 0; ntl < 2; ++ntl) {
                        f32x4 acc = MFMA32(a30, b3[ntl * 2 + 0], bi3);
                        acc = MFMA32(a31, b3[ntl * 2 + 1], acc);
                        st4h(&sc[((ntl * 2 + ((mtc >> 1) & 1)) * 64 +
                                  ((mtc & 1) * 2 + (q >> 1)) * 16 + c) * 8 + (q & 1) * 4],
                             gelu_pk(pkrtz(acc[0], acc[1])), gelu_pk(pkrtz(acc[2], acc[3])));
                    }
                }
                h16x8 a4[2][2];
#pragma unroll
                for (int mt = 0; mt < 2; ++mt)
#pragma unroll
                    for (int kk = 0; kk < 2; ++kk)
                        a4[mt][kk] = *(const h16x8*)&sc[((mt * 2 + kk) * 64 + lane) * 8];
#pragma unroll
                for (int nt = 0; nt < 4; ++nt) {
                    const h16x8 b40 = *(const h16x8*)(B4L + il * 8192 + (nt * 4 + hh * 2 + 0) * 512 + lane * 8);
                    const h16x8 b41 = *(const h16x8*)(B4L + il * 8192 + (nt * 4 + hh * 2 + 1) * 512 + lane * 8);
#pragma unroll
                    for (int mt = 0; mt < 2; ++mt) {
                        tok[mt][nt] = MFMA32(a4[mt][0], b40, tok[mt][nt]);
                        tok[mt][nt] = MFMA32(a4[mt][1], b41, tok[mt][nt]);
                    }
                }
            }
        }  // il

        // ======== head ========
        {
            f32x4 mean[2], rsig[2];
            stats(mean, rsig);
#pragma unroll
            for (int mt = 0; mt < 2; ++mt) {
                f32x4 l4 = (tok[mt][0] - mean[mt]) * f4s(gh_r[0]);
                l4 = __builtin_elementwise_fma(tok[mt][1] - mean[mt], f4s(gh_r[1]), l4);
                l4 = __builtin_elementwise_fma(tok[mt][2] - mean[mt], f4s(gh_r[2]), l4);
                l4 = __builtin_elementwise_fma(tok[mt][3] - mean[mt], f4s(gh_r[3]), l4);
                f32x4 ls;
#pragma unroll
                for (int r = 0; r < 4; ++r) ls[r] = rowsum16(l4[r]);
                f32x4 nv = cur8[mt] + __builtin_elementwise_fma(rsig[mt], ls, f4s(bh));
                nv = __builtin_elementwise_min(__builtin_elementwise_max(nv, f4s(0.f)), f4s(1.f));
                cur8[mt] = nv;
            }
            if (c == 0) {
                float* op = out + ((size_t)b * Tt + t) * 32 + q * 4;
                *(f32x4*)(op) = cur8[0];
                *(f32x4*)(op + 16) = cur8[1];
            }
        }
    }  // t
}
}  // namespace

extern "C" void kernel_launch(void* const* d_in, const int* in_sizes, int n_in,
                              void* d_out, int out_size, void* d_ws, size_t ws_size,
                              hipStream_t stream) {
    (void)in_sizes; (void)n_in; (void)ws_size; (void)out_size;
    const float* phys    = (const float*)d_in[0];
    const float* latents = (const float*)d_in[1];
    const float* pos_emb = (const float*)d_in[2];
    const float* tokW    = (const float*)d_in[3];
    const float* tokb    = (const float*)d_in[4];
    const float* physW1  = (const float*)d_in[5];
    const float* physb1  = (const float*)d_in[6];
    const float* physW2  = (const float*)d_in[7];
    const float* physb2  = (const float*)d_in[8];
    const float* tn_g    = (const float*)d_in[9];
    const float* tn_b    = (const float*)d_in[10];
    const float* tiW     = (const float*)d_in[11];
    const float* tib     = (const float*)d_in[12];
    const float* toW     = (const float*)d_in[13];
    const float* tob     = (const float*)d_in[14];
    const float* cn_g    = (const float*)d_in[15];
    const float* cn_b    = (const float*)d_in[16];
    const float* ciW     = (const float*)d_in[17];
    const float* cib     = (const float*)d_in[18];
    const float* coW     = (const float*)d_in[19];
    const float* cob     = (const float*)d_in[20];
    const float* hn_g    = (const float*)d_in[21];
    const float* hn_b    = (const float*)d_in[22];
    const float* headW   = (const float*)d_in[23];
    const float* headb   = (const float*)d_in[24];

    lno_prep<<<dim3(256), dim3(256), 0, stream>>>(tiW, toW, ciW, coW, physW2, (short*)d_ws);
    lno_phys<<<dim3(131072), dim3(256), 0, stream>>>(phys, physW1, physb1, physW2, physb2,
                                                     (short*)d_out);
    // scan: 256 blocks (1/CU), 8 waves/block = 8 independent batches
    lno_scan<<<dim3(256), dim3(512), 0, stream>>>(
        latents, pos_emb, tokW, tokb, tn_g, tn_b, tib, tob,
        cn_g, cn_b, cib, cob, hn_g, hn_b, headW, headb,
        (const short*)d_ws, (const short*)d_out, (float*)d_out);
}